// Round 1
// baseline (1593.587 us; speedup 1.0000x reference)
//
#include <hip/hip_runtime.h>

#define NN 65536
#define EE 262144
#define DT 128

typedef unsigned short u16;
typedef short bf8_t __attribute__((ext_vector_type(8)));
typedef float f32x4 __attribute__((ext_vector_type(4)));

#define GM_BIAS   1
#define GM_GELU_A 2
#define GM_BF16O  4
#define GM_ACCUM  8
#define GM_AREL   16

__device__ __forceinline__ float lrelu(float x){ return x > 0.f ? x : 0.2f*x; }
__device__ __forceinline__ float gelu_exact(float x){ return 0.5f*x*(1.f+erff(x*0.70710678118654752f)); }
__device__ __forceinline__ u16 f2bf(float f){
    union { float f; unsigned u; } v; v.f = f;
    unsigned u = v.u;
    unsigned r = (u + 0x7FFFu + ((u >> 16) & 1u)) >> 16;
    return (u16)r;
}
__device__ __forceinline__ float bf2f(u16 b){
    union { unsigned u; float f; } v; v.u = ((unsigned)b) << 16; return v.f;
}

// ---------------- GEMM: C[M=65536,128] = A[*,128] @ W[128,128] variants ----------------
template<int FLAGS>
__global__ __launch_bounds__(256) void gemm128(const float* __restrict__ A,
    const float* __restrict__ W, const float* __restrict__ bias,
    float* __restrict__ Cf, u16* __restrict__ Cb)
{
    __shared__ __align__(16) u16 Wt[128][136];   // Wt[n][k] = W[k][n] (bf16)
    __shared__ __align__(16) u16 As[64][136];
    const int tid = threadIdx.x;
    const int bm = blockIdx.x * 64;
    for (int idx = tid; idx < 128*128; idx += 256) {
        int n = idx >> 7, k = idx & 127;
        float w;
        if (FLAGS & GM_AREL) {
            int h = n >> 5, f = n & 31, h2 = k >> 5, d2 = k & 31;
            w = (h == h2) ? W[(h*32 + d2)*32 + f] : 0.f;
        } else {
            w = W[k*128 + n];
        }
        Wt[n][k] = f2bf(w);
    }
    for (int idx = tid; idx < 64*128; idx += 256) {
        int r = idx >> 7, k = idx & 127;
        float v = A[(size_t)(bm + r)*128 + k];
        if (FLAGS & GM_GELU_A) v = gelu_exact(v);
        As[r][k] = f2bf(v);
    }
    __syncthreads();
    const int wave = tid >> 6, lane = tid & 63;
    const int r0 = wave * 16;
    const int lr = lane & 15, lk = lane >> 4;
    f32x4 acc[8];
    #pragma unroll
    for (int i = 0; i < 8; ++i) acc[i] = (f32x4){0.f,0.f,0.f,0.f};
    #pragma unroll
    for (int kk = 0; kk < 4; ++kk) {
        bf8_t af = *(const bf8_t*)&As[r0 + lr][kk*32 + lk*8];
        #pragma unroll
        for (int nt = 0; nt < 8; ++nt) {
            bf8_t bfr = *(const bf8_t*)&Wt[nt*16 + lr][kk*32 + lk*8];
            acc[nt] = __builtin_amdgcn_mfma_f32_16x16x32_bf16(af, bfr, acc[nt], 0, 0, 0);
        }
    }
    const int rbase = bm + r0 + lk*4;
    #pragma unroll
    for (int nt = 0; nt < 8; ++nt) {
        int col = nt*16 + lr;
        float badd = (FLAGS & GM_BIAS) ? bias[col] : 0.f;
        #pragma unroll
        for (int i = 0; i < 4; ++i) {
            size_t o = (size_t)(rbase + i)*128 + col;
            float v = acc[nt][i] + badd;
            if (FLAGS & GM_BF16O) {
                Cb[o] = f2bf(v);
            } else {
                if (FLAGS & GM_ACCUM) v += Cf[o];
                Cf[o] = v;
            }
        }
    }
}

// ---------------- CSR build ----------------
__global__ __launch_bounds__(256) void hist_k(const int* __restrict__ ei, int* __restrict__ cnt){
    int gid = blockIdx.x*256 + threadIdx.x;
    int t = gid / EE, e = gid - t*EE;
    int d = ei[t*2*EE + EE + e];
    atomicAdd(&cnt[t*NN + d], 1);
}

__global__ __launch_bounds__(256) void scan1_k(const int* __restrict__ cnt, int* __restrict__ off, int* __restrict__ parts){
    __shared__ int sums[256];
    int b = blockIdx.x; int t = b >> 6; int base = (b & 63) * 1024;
    int tid = threadIdx.x;
    int v[4]; int tsum = 0;
    int gbase = t*NN + base + tid*4;
    #pragma unroll
    for (int i = 0; i < 4; ++i){ v[i] = cnt[gbase+i]; tsum += v[i]; }
    sums[tid] = tsum; __syncthreads();
    for (int ofs = 1; ofs < 256; ofs <<= 1) {
        int a = (tid >= ofs) ? sums[tid-ofs] : 0;
        __syncthreads();
        sums[tid] += a;
        __syncthreads();
    }
    int run = sums[tid] - tsum;
    int obase = t*(NN+1) + base + tid*4;
    #pragma unroll
    for (int i = 0; i < 4; ++i){ off[obase+i] = run; run += v[i]; }
    if (tid == 255) parts[b] = sums[255];
}

__global__ void scan2_k(int* parts){
    if (threadIdx.x == 0 && blockIdx.x == 0) {
        for (int t = 0; t < 3; ++t) {
            int run = 0;
            for (int i = 0; i < 64; ++i) { int b = t*64+i; int v = parts[b]; parts[b] = run; run += v; }
        }
    }
}

__global__ __launch_bounds__(256) void scan3_k(int* __restrict__ off, const int* __restrict__ parts){
    int b = blockIdx.x; int t = b >> 6; int base = (b & 63) * 1024;
    int add = parts[b];
    int idx = t*(NN+1) + base + threadIdx.x*4;
    #pragma unroll
    for (int i = 0; i < 4; ++i) off[idx+i] += add;
    if (threadIdx.x == 0 && (b & 63) == 0) off[t*(NN+1) + NN] = EE;
}

__global__ __launch_bounds__(256) void scatter_k(const int* __restrict__ ei, const int* __restrict__ off,
                                                 int* __restrict__ cur, int* __restrict__ out){
    int gid = blockIdx.x*256 + threadIdx.x;
    int t = gid / EE, e = gid - t*EE;
    int s = ei[t*2*EE + e];
    int d = ei[t*2*EE + EE + e];
    int p = atomicAdd(&cur[t*NN + d], 1);
    out[t*EE + off[t*(NN+1)+d] + p] = s;
}

// ---------------- GAT ----------------
__global__ __launch_bounds__(256) void gat_alpha_k(const float* __restrict__ h,
    const float* __restrict__ asrc, const float* __restrict__ adst,
    float* __restrict__ als, float* __restrict__ ald)
{
    int gid = blockIdx.x*256 + threadIdx.x;
    int node = gid >> 6, lane = gid & 63;
    int g = lane >> 4, dd = (lane & 15)*2;
    float2 hv = *(const float2*)&h[(size_t)node*128 + lane*2];
    float s = hv.x*asrc[g*32+dd] + hv.y*asrc[g*32+dd+1];
    float d = hv.x*adst[g*32+dd] + hv.y*adst[g*32+dd+1];
    #pragma unroll
    for (int o = 1; o < 16; o <<= 1){ s += __shfl_xor(s,o); d += __shfl_xor(d,o); }
    if ((lane & 15) == 0){ als[node*4+g] = s; ald[node*4+g] = d; }
}

__global__ __launch_bounds__(256) void gat_agg_k(const float* __restrict__ h,
    const float* __restrict__ als, const float* __restrict__ ald,
    const int* __restrict__ off, const int* __restrict__ srcs,
    float* __restrict__ acc)
{
    int gid = blockIdx.x*256 + threadIdx.x;
    int node = gid >> 6, lane = gid & 63;
    int g = lane >> 4;
    float ad = ald[node*4+g];
    float aself = als[node*4+g];
    int beg = off[node], end = off[node+1];
    float m = lrelu(aself + ad);
    for (int e = beg; e < end; ++e) {
        int s = srcs[e];
        m = fmaxf(m, lrelu(als[s*4+g] + ad));
    }
    float dsum = 0.f, a0 = 0.f, a1 = 0.f;
    {
        float ex = expf(lrelu(aself + ad) - m);
        dsum += ex;
        float2 hv = *(const float2*)&h[(size_t)node*128 + lane*2];
        a0 += ex*hv.x; a1 += ex*hv.y;
    }
    for (int e = beg; e < end; ++e) {
        int s = srcs[e];
        float ex = expf(lrelu(als[s*4+g] + ad) - m);
        dsum += ex;
        float2 hv = *(const float2*)&h[(size_t)s*128 + lane*2];
        a0 += ex*hv.x; a1 += ex*hv.y;
    }
    float inv = 1.f/(dsum + 1e-16f);
    size_t o = (size_t)node*128 + lane*2;
    acc[o]   += a0*inv;
    acc[o+1] += a1*inv;
}

// x_out = leaky( x_old + scale * xnew * rsqrt(mean(xnew^2)+eps) ), xnew += sum of 3 bias rows
__global__ __launch_bounds__(256) void res_k(const float* __restrict__ xold,
    const float* __restrict__ xnew, const float* __restrict__ scale,
    const float* __restrict__ bias3, float* __restrict__ out)
{
    int gid = blockIdx.x*256 + threadIdx.x;
    int node = gid >> 6, lane = gid & 63;
    int c0 = lane*2;
    size_t o = (size_t)node*128 + c0;
    float2 v = *(const float2*)&xnew[o];
    v.x += bias3[c0]   + bias3[128+c0]   + bias3[256+c0];
    v.y += bias3[c0+1] + bias3[128+c0+1] + bias3[256+c0+1];
    float ss = v.x*v.x + v.y*v.y;
    #pragma unroll
    for (int of = 1; of < 64; of <<= 1) ss += __shfl_xor(ss, of);
    float r = rsqrtf(ss*(1.f/128.f) + 1e-6f);
    float2 xo = *(const float2*)&xold[o];
    float y0 = xo.x + scale[c0]*v.x*r;
    float y1 = xo.y + scale[c0+1]*v.y*r;
    out[o] = lrelu(y0); out[o+1] = lrelu(y1);
}

// ---------------- HGT ----------------
__global__ __launch_bounds__(256) void hgt_agg_k(const u16* __restrict__ kt,
    const u16* __restrict__ vt, const float* __restrict__ q,
    const float* __restrict__ prel, const int* __restrict__ off,
    const int* __restrict__ srcs, float* __restrict__ agg)
{
    int gid = blockIdx.x*256 + threadIdx.x;
    int node = gid >> 6, lane = gid & 63;
    int hh = lane >> 4;
    float2 qv = *(const float2*)&q[(size_t)node*128 + lane*2];
    float m = -1e30f, dsum = 0.f, a0 = 0.f, a1 = 0.f;
    for (int t = 0; t < 3; ++t) {
        float ph = prel[t*4+hh] * 0.17677669529663689f; // 1/sqrt(32)
        int beg = off[t*(NN+1)+node], end = off[t*(NN+1)+node+1];
        for (int e = beg; e < end; ++e) {
            int s = srcs[t*EE + e];
            size_t ro = ((size_t)t*NN + s)*128 + lane*2;
            float k0 = bf2f(kt[ro]), k1 = bf2f(kt[ro+1]);
            float sc = qv.x*k0 + qv.y*k1;
            #pragma unroll
            for (int o = 1; o < 16; o <<= 1) sc += __shfl_xor(sc, o);
            sc *= ph;
            float mn = fmaxf(m, sc);
            float rs = expf(m - mn);
            float ex = expf(sc - mn);
            float v0 = bf2f(vt[ro]), v1 = bf2f(vt[ro+1]);
            dsum = dsum*rs + ex;
            a0 = a0*rs + ex*v0;
            a1 = a1*rs + ex*v1;
            m = mn;
        }
    }
    float inv = 1.f/(dsum + 1e-16f);
    size_t o = (size_t)node*128 + lane*2;
    agg[o] = a0*inv; agg[o+1] = a1*inv;
}

__global__ __launch_bounds__(256) void hgt_res_k(const float* __restrict__ x2,
    const float* __restrict__ hraw, const float* __restrict__ skipp,
    const float* __restrict__ scale, float* __restrict__ out)
{
    int gid = blockIdx.x*256 + threadIdx.x;
    int node = gid >> 6, lane = gid & 63;
    float sig = 1.f/(1.f + expf(-skipp[0]));
    size_t o = (size_t)node*128 + lane*2;
    int c0 = lane*2;
    float2 hv = *(const float2*)&hraw[o];
    float2 xv = *(const float2*)&x2[o];
    float v0 = sig*hv.x + (1.f-sig)*xv.x;
    float v1 = sig*hv.y + (1.f-sig)*xv.y;
    float ss = v0*v0 + v1*v1;
    #pragma unroll
    for (int of = 1; of < 64; of <<= 1) ss += __shfl_xor(ss, of);
    float r = rsqrtf(ss*(1.f/128.f) + 1e-6f);
    float y0 = xv.x + scale[c0]*v0*r;
    float y1 = xv.y + scale[c0+1]*v1*r;
    out[o] = lrelu(y0); out[o+1] = lrelu(y1);
}

// ---------------- FiLM ----------------
__global__ __launch_bounds__(256) void film_small_k(const float* __restrict__ z,
    const float* __restrict__ W1, const float* __restrict__ b1,
    const float* __restrict__ W2, const float* __restrict__ b2,
    float* __restrict__ gb, int B)
{
    __shared__ float g1[32*256];
    int tid = threadIdx.x;
    for (int idx = tid; idx < B*256; idx += 256) {
        int r = idx >> 8, c = idx & 255;
        float s = b1[c];
        for (int k = 0; k < 128; ++k) s += z[r*128+k]*W1[k*256+c];
        g1[idx] = gelu_exact(s);
    }
    __syncthreads();
    for (int idx = tid; idx < B*256; idx += 256) {
        int r = idx >> 8, c = idx & 255;
        float s = b2[c];
        for (int k = 0; k < 256; ++k) s += g1[r*256+k]*W2[k*256+c];
        gb[idx] = 0.1f*tanhf(s);
    }
}

__global__ __launch_bounds__(256) void film_apply_k(float* __restrict__ out,
    const float* __restrict__ gb, const int* __restrict__ bszp)
{
    int gid = blockIdx.x*256 + threadIdx.x;
    int bsz = *bszp;
    int c = NN / bsz;
    size_t base = (size_t)gid*4;
    int row = (int)(base >> 7);
    int col = (int)(base & 127);
    int b = row / c;
    float4 x = *(float4*)&out[base];
    const float* gr = gb + b*256;
    float4 ga = *(const float4*)&gr[col];
    float4 be = *(const float4*)&gr[128+col];
    x.x = (1.f+ga.x)*x.x + be.x;
    x.y = (1.f+ga.y)*x.y + be.y;
    x.z = (1.f+ga.z)*x.z + be.z;
    x.w = (1.f+ga.w)*x.w + be.w;
    *(float4*)&out[base] = x;
}

// ---------------- launch ----------------
extern "C" void kernel_launch(void* const* d_in, const int* in_sizes, int n_in,
                              void* d_out, int out_size, void* d_ws, size_t ws_size,
                              hipStream_t stream)
{
    const float* x_cell = (const float*)d_in[0];
    const float* z_h    = (const float*)d_in[1];
    const float* x_emb  = (const float*)d_in[2];
    const int*   eidx   = (const int*)d_in[3];
    const int*   bszp   = (const int*)d_in[4];
    const float* g1W  = (const float*)d_in[5];
    const float* g1as = (const float*)d_in[6];
    const float* g1ad = (const float*)d_in[7];
    const float* g1b  = (const float*)d_in[8];
    const float* g2W  = (const float*)d_in[9];
    const float* g2as = (const float*)d_in[10];
    const float* g2ad = (const float*)d_in[11];
    const float* g2b  = (const float*)d_in[12];
    const float* n1s  = (const float*)d_in[13];
    const float* n2s  = (const float*)d_in[14];
    const float* n3s  = (const float*)d_in[15];
    const float* Wk   = (const float*)d_in[16];
    const float* bk   = (const float*)d_in[17];
    const float* Wq   = (const float*)d_in[18];
    const float* bq   = (const float*)d_in[19];
    const float* Wv   = (const float*)d_in[20];
    const float* bv   = (const float*)d_in[21];
    const float* arel = (const float*)d_in[22];
    const float* mrel = (const float*)d_in[23];
    const float* prel = (const float*)d_in[24];
    const float* Wo   = (const float*)d_in[25];
    const float* bo   = (const float*)d_in[26];
    const float* skipp= (const float*)d_in[27];
    const float* injW = (const float*)d_in[28];
    const float* injb = (const float*)d_in[29];
    const float* fW1  = (const float*)d_in[30];
    const float* fb1  = (const float*)d_in[31];
    const float* fW2  = (const float*)d_in[32];
    const float* fb2  = (const float*)d_in[33];

    const size_t ND = (size_t)NN * 128;
    float* ws  = (float*)d_ws;
    float* x2  = ws;
    float* Cb  = ws + ND;
    float* Db  = ws + 2*ND;
    float* Eb  = ws + 3*ND;
    u16* ktb = (u16*)(ws + 4*ND);
    u16* vtb = ktb + 3*ND;
    float* als  = (float*)(vtb + 3*ND);
    float* ald  = als + (size_t)NN*4;
    float* gbuf = ald + (size_t)NN*4;
    int* coff  = (int*)(gbuf + 32*256);
    int* csrc  = coff + 3*(NN+1);
    int* tmpc  = csrc + 3*EE;
    int* parts = tmpc + 3*NN;
    float* x1 = (float*)d_out;
    float* outp = (float*)d_out;

    // ---- CSR build (shared by GAT1, GAT2, HGT) ----
    hipMemsetAsync(tmpc, 0, 3*NN*sizeof(int), stream);
    hist_k<<<3*EE/256, 256, 0, stream>>>(eidx, tmpc);
    scan1_k<<<192, 256, 0, stream>>>(tmpc, coff, parts);
    scan2_k<<<1, 64, 0, stream>>>(parts);
    scan3_k<<<192, 256, 0, stream>>>(coff, parts);
    hipMemsetAsync(tmpc, 0, 3*NN*sizeof(int), stream);
    scatter_k<<<3*EE/256, 256, 0, stream>>>(eidx, coff, tmpc, csrc);

    // ---- GAT layer 1 ----
    hipMemsetAsync(Db, 0, ND*sizeof(float), stream);
    for (int t = 0; t < 3; ++t) {
        gemm128<0><<<1024,256,0,stream>>>(x_cell, g1W + t*16384, nullptr, Cb, nullptr);
        gat_alpha_k<<<16384,256,0,stream>>>(Cb, g1as + t*128, g1ad + t*128, als, ald);
        gat_agg_k<<<16384,256,0,stream>>>(Cb, als, ald, coff + t*(NN+1), csrc + (size_t)t*EE, Db);
    }
    res_k<<<16384,256,0,stream>>>(x_cell, Db, n1s, g1b, x1);

    // ---- GAT layer 2 ----
    hipMemsetAsync(Db, 0, ND*sizeof(float), stream);
    for (int t = 0; t < 3; ++t) {
        gemm128<0><<<1024,256,0,stream>>>(x1, g2W + t*16384, nullptr, Cb, nullptr);
        gat_alpha_k<<<16384,256,0,stream>>>(Cb, g2as + t*128, g2ad + t*128, als, ald);
        gat_agg_k<<<16384,256,0,stream>>>(Cb, als, ald, coff + t*(NN+1), csrc + (size_t)t*EE, Db);
    }
    res_k<<<16384,256,0,stream>>>(x1, Db, n2s, g2b, x2);

    // ---- HGT ----
    gemm128<GM_BIAS><<<1024,256,0,stream>>>(x2, Wk, bk, Cb, nullptr);  // k
    gemm128<GM_BIAS><<<1024,256,0,stream>>>(x2, Wq, bq, Db, nullptr);  // q
    gemm128<GM_BIAS><<<1024,256,0,stream>>>(x2, Wv, bv, Eb, nullptr);  // v
    for (int t = 0; t < 3; ++t) {
        gemm128<GM_AREL|GM_BF16O><<<1024,256,0,stream>>>(Cb, arel + t*4096, nullptr, nullptr, ktb + (size_t)t*ND);
        gemm128<GM_AREL|GM_BF16O><<<1024,256,0,stream>>>(Eb, mrel + t*4096, nullptr, nullptr, vtb + (size_t)t*ND);
    }
    hgt_agg_k<<<16384,256,0,stream>>>(ktb, vtb, Db, prel, coff, csrc, Cb);      // agg -> Cb
    gemm128<GM_BIAS|GM_GELU_A><<<1024,256,0,stream>>>(Cb, Wo, bo, Db, nullptr); // gelu(agg)@Wo -> Db
    hgt_res_k<<<16384,256,0,stream>>>(x2, Db, skipp, n3s, outp);                // x3 -> d_out

    // ---- inject ----
    gemm128<GM_BIAS|GM_ACCUM><<<1024,256,0,stream>>>(x_emb, injW, injb, outp, nullptr);

    // ---- FiLM ----
    int B = in_sizes[1] / 128;
    film_small_k<<<1,256,0,stream>>>(z_h, fW1, fb1, fW2, fb2, gbuf, B);
    film_apply_k<<<(NN*128/4)/256, 256, 0, stream>>>(outp, gbuf, bszp);
}

// Round 2
// 992.349 us; speedup vs baseline: 1.6059x; 1.6059x over previous
//
#include <hip/hip_runtime.h>

#define NN 65536
#define EE 262144
#define ND ((size_t)NN * 128)

typedef unsigned short u16;
typedef short bf8_t __attribute__((ext_vector_type(8)));
typedef float f32x4 __attribute__((ext_vector_type(4)));

__device__ __forceinline__ float lrelu(float x){ return x > 0.f ? x : 0.2f*x; }
__device__ __forceinline__ float gelu_exact(float x){ return 0.5f*x*(1.f+erff(x*0.70710678118654752f)); }
__device__ __forceinline__ u16 f2bf(float f){
    union { float f; unsigned u; } v; v.f = f;
    unsigned u = v.u;
    return (u16)((u + 0x7FFFu + ((u >> 16) & 1u)) >> 16);
}
__device__ __forceinline__ float bf2f(u16 b){
    union { unsigned u; float f; } v; v.u = ((unsigned)b) << 16; return v.f;
}
__device__ __forceinline__ float2 bf2x(unsigned p){
    union { unsigned u; float f; } a, b;
    a.u = (p & 0xFFFFu) << 16; b.u = p & 0xFFFF0000u;
    return make_float2(a.f, b.f);
}

// ================= GEMM building blocks =================
__device__ __forceinline__ void stage_W(u16 (*Wt)[136], const float* __restrict__ W, int tid){
    for (int idx = tid; idx < 128*128; idx += 256){
        int n = idx >> 7, k = idx & 127;
        Wt[n][k] = f2bf(W[k*128 + n]);
    }
}
__device__ __forceinline__ void stage_W_rel(u16 (*Wt)[136], const float* __restrict__ W, int tid){
    for (int idx = tid; idx < 128*128; idx += 256){
        int n = idx >> 7, k = idx & 127;
        int h = n >> 5, f = n & 31, h2 = k >> 5, d2 = k & 31;
        Wt[n][k] = f2bf((h == h2) ? W[(h*32 + d2)*32 + f] : 0.f);
    }
}
__device__ __forceinline__ void stage_A_f32(u16 (*As)[136], const float* __restrict__ A, size_t bm, int tid){
    for (int idx = tid; idx < 64*128; idx += 256){
        int r = idx >> 7, k = idx & 127;
        As[r][k] = f2bf(A[(bm + r)*128 + k]);
    }
}
__device__ __forceinline__ void stage_A_bf16(u16 (*As)[136], const u16* __restrict__ A, size_t bm, int tid){
    for (int idx = tid; idx < 64*64; idx += 256){
        int r = idx >> 6, k2 = idx & 63;
        unsigned v = ((const unsigned*)A)[(bm + r)*64 + k2];
        *(unsigned*)&As[r][k2*2] = v;
    }
}
__device__ __forceinline__ void mfma8(const u16 (*As)[136], const u16 (*Wt)[136],
                                      int wave, int lane, f32x4* acc){
    int r0 = wave*16, lr = lane & 15, lk = lane >> 4;
    #pragma unroll
    for (int i = 0; i < 8; ++i) acc[i] = (f32x4){0.f,0.f,0.f,0.f};
    #pragma unroll
    for (int kk = 0; kk < 4; ++kk) {
        bf8_t af = *(const bf8_t*)&As[r0 + lr][kk*32 + lk*8];
        #pragma unroll
        for (int nt = 0; nt < 8; ++nt) {
            bf8_t bfr = *(const bf8_t*)&Wt[nt*16 + lr][kk*32 + lk*8];
            acc[nt] = __builtin_amdgcn_mfma_f32_16x16x32_bf16(af, bfr, acc[nt], 0, 0, 0);
        }
    }
}

// ---- GAT projection: h_t = x @ W_t for t=0..2 (bf16 out) + fused alpha_src/dst ----
__global__ __launch_bounds__(256) void gat_gemm3_k(const float* __restrict__ X,
    const float* __restrict__ Wb, const float* __restrict__ asrcb, const float* __restrict__ adstb,
    u16* __restrict__ hb, float* __restrict__ alsb, float* __restrict__ aldb)
{
    __shared__ __align__(16) u16 Wt[128][136];
    __shared__ __align__(16) u16 As[64][136];
    const int tid = threadIdx.x;
    const size_t bm = (size_t)blockIdx.x * 64;
    stage_A_f32(As, X, bm, tid);
    const int wave = tid >> 6, lane = tid & 63, lr = lane & 15, lk = lane >> 4;
    f32x4 acc[8];
    for (int t = 0; t < 3; ++t) {
        __syncthreads();                       // As ready / prev alpha done with Wt space
        stage_W(Wt, Wb + t*16384, tid);
        __syncthreads();
        mfma8(As, Wt, wave, lane, acc);
        // global h write (bf16)
        u16* h = hb + (size_t)t*ND;
        const int rbase = (int)bm + wave*16 + lk*4;
        #pragma unroll
        for (int nt = 0; nt < 8; ++nt) {
            int col = nt*16 + lr;
            #pragma unroll
            for (int i = 0; i < 4; ++i)
                h[(size_t)(rbase + i)*128 + col] = f2bf(acc[nt][i]);
        }
        __syncthreads();                       // all waves done reading Wt
        // reuse Wt space as Hs[64][136] for alpha reduction
        u16 (*Hs)[136] = Wt;
        {
            int lrow = wave*16 + lk*4;
            #pragma unroll
            for (int nt = 0; nt < 8; ++nt) {
                int col = nt*16 + lr;
                #pragma unroll
                for (int i = 0; i < 4; ++i) Hs[lrow + i][col] = f2bf(acc[nt][i]);
            }
        }
        __syncthreads();
        // alpha: thread -> (row=tid>>2, g=tid&3)
        {
            int row = tid >> 2, g = tid & 3;
            const float* as = asrcb + t*128 + g*32;
            const float* ad = adstb + t*128 + g*32;
            float ss = 0.f, sd = 0.f;
            #pragma unroll
            for (int d = 0; d < 32; ++d) {
                float hv = bf2f(Hs[row][g*32 + d]);
                ss += hv * as[d];
                sd += hv * ad[d];
            }
            size_t gi = ((size_t)t*NN + bm + row)*4 + g;
            alsb[gi] = ss; aldb[gi] = sd;
        }
    }
}

// ---- K/Q/V: three GEMMs sharing staged A, bf16 out + bias ----
__global__ __launch_bounds__(256) void gemm_kqv_k(const float* __restrict__ X,
    const float* __restrict__ Wk, const float* __restrict__ bk,
    const float* __restrict__ Wq, const float* __restrict__ bq,
    const float* __restrict__ Wv, const float* __restrict__ bv,
    u16* __restrict__ kb, u16* __restrict__ qb, u16* __restrict__ vb)
{
    __shared__ __align__(16) u16 Wt[128][136];
    __shared__ __align__(16) u16 As[64][136];
    const int tid = threadIdx.x;
    const size_t bm = (size_t)blockIdx.x * 64;
    stage_A_f32(As, X, bm, tid);
    const int wave = tid >> 6, lane = tid & 63, lr = lane & 15, lk = lane >> 4;
    const float* Ws[3] = {Wk, Wq, Wv};
    const float* bs[3] = {bk, bq, bv};
    u16* outs[3] = {kb, qb, vb};
    f32x4 acc[8];
    for (int w = 0; w < 3; ++w) {
        __syncthreads();
        stage_W(Wt, Ws[w], tid);
        __syncthreads();
        mfma8(As, Wt, wave, lane, acc);
        u16* o = outs[w];
        const float* bias = bs[w];
        const int rbase = (int)bm + wave*16 + lk*4;
        #pragma unroll
        for (int nt = 0; nt < 8; ++nt) {
            int col = nt*16 + lr;
            float badd = bias[col];
            #pragma unroll
            for (int i = 0; i < 4; ++i)
                o[(size_t)(rbase + i)*128 + col] = f2bf(acc[nt][i] + badd);
        }
    }
}

// ---- rel transforms: kt_t = k @ blockdiag(arel_t), vt_t = v @ blockdiag(mrel_t) ----
__global__ __launch_bounds__(256) void gemm_rel6_k(const u16* __restrict__ kb, const u16* __restrict__ vb,
    const float* __restrict__ arel, const float* __restrict__ mrel,
    u16* __restrict__ ktb, u16* __restrict__ vtb)
{
    __shared__ __align__(16) u16 Wt[128][136];
    __shared__ __align__(16) u16 As[64][136];
    const int tid = threadIdx.x;
    const size_t bm = (size_t)blockIdx.x * 64;
    const int wave = tid >> 6, lane = tid & 63, lr = lane & 15, lk = lane >> 4;
    f32x4 acc[8];
    stage_A_bf16(As, kb, bm, tid);
    for (int p = 0; p < 2; ++p) {
        const float* W6 = p ? mrel : arel;
        u16* O6 = p ? vtb : ktb;
        for (int t = 0; t < 3; ++t) {
            __syncthreads();
            stage_W_rel(Wt, W6 + t*4096, tid);
            __syncthreads();
            mfma8(As, Wt, wave, lane, acc);
            u16* o = O6 + (size_t)t*ND;
            const int rbase = (int)bm + wave*16 + lk*4;
            #pragma unroll
            for (int nt = 0; nt < 8; ++nt) {
                int col = nt*16 + lr;
                #pragma unroll
                for (int i = 0; i < 4; ++i)
                    o[(size_t)(rbase + i)*128 + col] = f2bf(acc[nt][i]);
            }
        }
        if (p == 0) { __syncthreads(); stage_A_bf16(As, vb, bm, tid); }
    }
}

// ---- Wo GEMM + HGT skip/rmsnorm residual epilogue -> out (f32) ----
__global__ __launch_bounds__(256) void gemm_wo_res_k(const u16* __restrict__ aggb,
    const float* __restrict__ Wo, const float* __restrict__ bo,
    const float* __restrict__ x2, const float* __restrict__ skipp,
    const float* __restrict__ scale, float* __restrict__ out)
{
    __shared__ __align__(16) u16 Wt[128][136];
    __shared__ __align__(16) u16 As[64][136];
    const int tid = threadIdx.x;
    const size_t bm = (size_t)blockIdx.x * 64;
    stage_A_bf16(As, aggb, bm, tid);
    stage_W(Wt, Wo, tid);
    __syncthreads();
    const int wave = tid >> 6, lane = tid & 63, lr = lane & 15, lk = lane >> 4;
    f32x4 acc[8];
    mfma8(As, Wt, wave, lane, acc);
    const float sig = 1.f/(1.f + expf(-skipp[0]));
    const int rbase = (int)bm + wave*16 + lk*4;
    float v[8][4], xv[8][4], ss[4] = {0.f,0.f,0.f,0.f};
    #pragma unroll
    for (int nt = 0; nt < 8; ++nt) {
        int col = nt*16 + lr;
        float badd = bo[col];
        #pragma unroll
        for (int i = 0; i < 4; ++i) {
            float h = acc[nt][i] + badd;
            float x = x2[(size_t)(rbase + i)*128 + col];
            float vv = sig*h + (1.f - sig)*x;
            v[nt][i] = vv; xv[nt][i] = x;
            ss[i] += vv*vv;
        }
    }
    #pragma unroll
    for (int i = 0; i < 4; ++i) {
        #pragma unroll
        for (int o = 1; o < 16; o <<= 1) ss[i] += __shfl_xor(ss[i], o);
    }
    #pragma unroll
    for (int nt = 0; nt < 8; ++nt) {
        int col = nt*16 + lr;
        float sc = scale[col];
        #pragma unroll
        for (int i = 0; i < 4; ++i) {
            float r = rsqrtf(ss[i]*(1.f/128.f) + 1e-6f);
            out[(size_t)(rbase + i)*128 + col] = lrelu(xv[nt][i] + sc*v[nt][i]*r);
        }
    }
}

// ---- inject GEMM + FiLM epilogue (in-place on out) ----
__global__ __launch_bounds__(256) void gemm_inj_film_k(const float* __restrict__ xemb,
    const float* __restrict__ injW, const float* __restrict__ injb,
    const float* __restrict__ gbuf, const int* __restrict__ bszp,
    float* __restrict__ out)
{
    __shared__ __align__(16) u16 Wt[128][136];
    __shared__ __align__(16) u16 As[64][136];
    const int tid = threadIdx.x;
    const size_t bm = (size_t)blockIdx.x * 64;
    stage_A_f32(As, xemb, bm, tid);
    stage_W(Wt, injW, tid);
    __syncthreads();
    const int wave = tid >> 6, lane = tid & 63, lr = lane & 15, lk = lane >> 4;
    f32x4 acc[8];
    mfma8(As, Wt, wave, lane, acc);
    const int bsz = *bszp;
    const int c = NN / bsz;
    const int rbase = (int)bm + wave*16 + lk*4;
    #pragma unroll
    for (int i = 0; i < 4; ++i) {
        int row = rbase + i;
        const float* gr = gbuf + (row / c)*256;
        #pragma unroll
        for (int nt = 0; nt < 8; ++nt) {
            int col = nt*16 + lr;
            size_t o = (size_t)row*128 + col;
            float h = acc[nt][i] + injb[col] + out[o];
            out[o] = (1.f + gr[col])*h + gr[128 + col];
        }
    }
}

// ================= CSR build =================
__global__ __launch_bounds__(256) void hist_k(const int* __restrict__ ei, int* __restrict__ cnt){
    int gid = blockIdx.x*256 + threadIdx.x;
    int t = gid / EE, e = gid - t*EE;
    int d = ei[t*2*EE + EE + e];
    atomicAdd(&cnt[t*NN + d], 1);
}
__global__ __launch_bounds__(256) void scan1_k(const int* __restrict__ cnt, int* __restrict__ off, int* __restrict__ parts){
    __shared__ int sums[256];
    int b = blockIdx.x; int t = b >> 6; int base = (b & 63) * 1024;
    int tid = threadIdx.x;
    int v[4]; int tsum = 0;
    int gbase = t*NN + base + tid*4;
    #pragma unroll
    for (int i = 0; i < 4; ++i){ v[i] = cnt[gbase+i]; tsum += v[i]; }
    sums[tid] = tsum; __syncthreads();
    for (int ofs = 1; ofs < 256; ofs <<= 1) {
        int a = (tid >= ofs) ? sums[tid-ofs] : 0;
        __syncthreads();
        sums[tid] += a;
        __syncthreads();
    }
    int run = sums[tid] - tsum;
    int obase = t*(NN+1) + base + tid*4;
    #pragma unroll
    for (int i = 0; i < 4; ++i){ off[obase+i] = run; run += v[i]; }
    if (tid == 255) parts[b] = sums[255];
}
__global__ void scan2_k(int* parts){
    if (threadIdx.x == 0 && blockIdx.x == 0) {
        for (int t = 0; t < 3; ++t) {
            int run = 0;
            for (int i = 0; i < 64; ++i) { int b = t*64+i; int v = parts[b]; parts[b] = run; run += v; }
        }
    }
}
__global__ __launch_bounds__(256) void scan3_k(int* __restrict__ off, const int* __restrict__ parts){
    int b = blockIdx.x; int t = b >> 6; int base = (b & 63) * 1024;
    int add = parts[b];
    int idx = t*(NN+1) + base + threadIdx.x*4;
    #pragma unroll
    for (int i = 0; i < 4; ++i) off[idx+i] += add;
    if (threadIdx.x == 0 && (b & 63) == 0) off[t*(NN+1) + NN] = EE;
}
__global__ __launch_bounds__(256) void scatter_k(const int* __restrict__ ei, const int* __restrict__ off,
                                                 int* __restrict__ cur, int* __restrict__ out){
    int gid = blockIdx.x*256 + threadIdx.x;
    int t = gid / EE, e = gid - t*EE;
    int s = ei[t*2*EE + e];
    int d = ei[t*2*EE + EE + e];
    int p = atomicAdd(&cur[t*NN + d], 1);
    out[t*EE + off[t*(NN+1)+d] + p] = s;
}

// ================= fused GAT aggregate (3 types) + bias + rmsnorm residual =================
__global__ __launch_bounds__(256) void gat_aggres_k(const u16* __restrict__ hb,
    const float* __restrict__ alsb, const float* __restrict__ aldb,
    const int* __restrict__ coff, const int* __restrict__ csrc,
    const float* __restrict__ bias3, const float* __restrict__ xold,
    const float* __restrict__ scale, float* __restrict__ out)
{
    int gid = blockIdx.x*256 + threadIdx.x;
    int node = gid >> 6, lane = gid & 63;
    int g = lane >> 4;
    float a0 = 0.f, a1 = 0.f;
    for (int t = 0; t < 3; ++t) {
        const u16* h = hb + (size_t)t*ND;
        const float* als = alsb + (size_t)t*NN*4;
        float ad = aldb[(size_t)t*NN*4 + node*4 + g];
        float aself = als[node*4 + g];
        int beg = coff[t*(NN+1) + node], end = coff[t*(NN+1) + node + 1];
        float ex = expf(lrelu(aself + ad));
        float dsum = ex;
        float2 hv = bf2x(*(const unsigned*)&h[(size_t)node*128 + lane*2]);
        float s0 = ex*hv.x, s1 = ex*hv.y;
        for (int e = beg; e < end; ++e) {
            int s = csrc[t*EE + e];
            float exx = expf(lrelu(als[s*4 + g] + ad));
            float2 hw = bf2x(*(const unsigned*)&h[(size_t)s*128 + lane*2]);
            dsum += exx; s0 += exx*hw.x; s1 += exx*hw.y;
        }
        float inv = 1.f/(dsum + 1e-16f);
        a0 += s0*inv; a1 += s1*inv;
    }
    int c0 = lane*2;
    a0 += bias3[c0]   + bias3[128+c0]   + bias3[256+c0];
    a1 += bias3[c0+1] + bias3[128+c0+1] + bias3[256+c0+1];
    float ssum = a0*a0 + a1*a1;
    #pragma unroll
    for (int o = 1; o < 64; o <<= 1) ssum += __shfl_xor(ssum, o);
    float r = rsqrtf(ssum*(1.f/128.f) + 1e-6f);
    size_t off = (size_t)node*128 + c0;
    float2 xo = *(const float2*)&xold[off];
    out[off]   = lrelu(xo.x + scale[c0]*a0*r);
    out[off+1] = lrelu(xo.y + scale[c0+1]*a1*r);
}

// ================= HGT aggregate (joint softmax over 3 types) + gelu, bf16 out =================
__global__ __launch_bounds__(256) void hgt_agg_k(const u16* __restrict__ ktb,
    const u16* __restrict__ vtb, const u16* __restrict__ qb,
    const float* __restrict__ prel, const int* __restrict__ coff,
    const int* __restrict__ csrc, u16* __restrict__ aggb)
{
    int gid = blockIdx.x*256 + threadIdx.x;
    int node = gid >> 6, lane = gid & 63;
    int hh = lane >> 4;
    float2 qv = bf2x(*(const unsigned*)&qb[(size_t)node*128 + lane*2]);
    float dsum = 0.f, a0 = 0.f, a1 = 0.f;
    for (int t = 0; t < 3; ++t) {
        float ph = prel[t*4 + hh] * 0.17677669529663689f;  // 1/sqrt(32)
        int beg = coff[t*(NN+1) + node], end = coff[t*(NN+1) + node + 1];
        const u16* kt = ktb + (size_t)t*ND;
        const u16* vt = vtb + (size_t)t*ND;
        for (int e = beg; e < end; ++e) {
            int s = csrc[t*EE + e];
            size_t ro = (size_t)s*128 + lane*2;
            float2 kv = bf2x(*(const unsigned*)&kt[ro]);
            float sc = qv.x*kv.x + qv.y*kv.y;
            #pragma unroll
            for (int o = 1; o < 16; o <<= 1) sc += __shfl_xor(sc, o);
            float ex = expf(sc * ph);
            float2 vv = bf2x(*(const unsigned*)&vt[ro]);
            dsum += ex; a0 += ex*vv.x; a1 += ex*vv.y;
        }
    }
    float inv = 1.f/(dsum + 1e-16f);
    size_t o = (size_t)node*128 + lane*2;
    aggb[o]   = f2bf(gelu_exact(a0*inv));
    aggb[o+1] = f2bf(gelu_exact(a1*inv));
}

// ================= FiLM small MLP: one block per batch row =================
__global__ __launch_bounds__(256) void film_k(const float* __restrict__ z,
    const float* __restrict__ W1, const float* __restrict__ b1,
    const float* __restrict__ W2, const float* __restrict__ b2,
    float* __restrict__ gb)
{
    __shared__ float zr[128];
    __shared__ float g1[256];
    int r = blockIdx.x, tid = threadIdx.x;
    if (tid < 128) zr[tid] = z[r*128 + tid];
    __syncthreads();
    float s = b1[tid];
    for (int k = 0; k < 128; ++k) s += zr[k]*W1[k*256 + tid];
    g1[tid] = gelu_exact(s);
    __syncthreads();
    float s2 = b2[tid];
    for (int k = 0; k < 256; ++k) s2 += g1[k]*W2[k*256 + tid];
    gb[r*256 + tid] = 0.1f*tanhf(s2);
}

// ================= launch =================
extern "C" void kernel_launch(void* const* d_in, const int* in_sizes, int n_in,
                              void* d_out, int out_size, void* d_ws, size_t ws_size,
                              hipStream_t stream)
{
    const float* x_cell = (const float*)d_in[0];
    const float* z_h    = (const float*)d_in[1];
    const float* x_emb  = (const float*)d_in[2];
    const int*   eidx   = (const int*)d_in[3];
    const int*   bszp   = (const int*)d_in[4];
    const float* g1W  = (const float*)d_in[5];
    const float* g1as = (const float*)d_in[6];
    const float* g1ad = (const float*)d_in[7];
    const float* g1b  = (const float*)d_in[8];
    const float* g2W  = (const float*)d_in[9];
    const float* g2as = (const float*)d_in[10];
    const float* g2ad = (const float*)d_in[11];
    const float* g2b  = (const float*)d_in[12];
    const float* n1s  = (const float*)d_in[13];
    const float* n2s  = (const float*)d_in[14];
    const float* n3s  = (const float*)d_in[15];
    const float* Wk   = (const float*)d_in[16];
    const float* bk   = (const float*)d_in[17];
    const float* Wq   = (const float*)d_in[18];
    const float* bq   = (const float*)d_in[19];
    const float* Wv   = (const float*)d_in[20];
    const float* bv   = (const float*)d_in[21];
    const float* arel = (const float*)d_in[22];
    const float* mrel = (const float*)d_in[23];
    const float* prel = (const float*)d_in[24];
    const float* Wo   = (const float*)d_in[25];
    const float* bo   = (const float*)d_in[26];
    const float* skipp= (const float*)d_in[27];
    const float* injW = (const float*)d_in[28];
    const float* injb = (const float*)d_in[29];
    const float* fW1  = (const float*)d_in[30];
    const float* fb1  = (const float*)d_in[31];
    const float* fW2  = (const float*)d_in[32];
    const float* fb2  = (const float*)d_in[33];

    float* ws   = (float*)d_ws;
    float* x2   = ws;                       // ND f32
    float* alsb = ws + ND;                  // 3*NN*4
    float* aldb = alsb + (size_t)3*NN*4;    // 3*NN*4
    float* gbuf = aldb + (size_t)3*NN*4;    // 32*256
    int* coff   = (int*)(gbuf + 32*256);    // 3*(NN+1)
    int* csrc   = coff + 3*(NN+1);          // 3*EE
    int* tmpc   = csrc + 3*EE;              // 3*NN
    int* parts  = tmpc + 3*NN;              // 192 (padded 256)
    u16* R1     = (u16*)(parts + 256);      // 3*ND u16: hb (GAT) -> k/q/v -> agg
    u16* R2     = R1 + 3*ND;                // 6*ND u16: kt[3], vt[3]

    u16* hb = R1;
    u16* kb = R1;
    u16* qb = R1 + ND;
    u16* vb = R1 + 2*ND;
    u16* ktb = R2;
    u16* vtb = R2 + 3*ND;
    u16* aggb = R1;                         // reuse k slot (dead after rel6)
    float* x1 = (float*)d_out;
    float* outp = (float*)d_out;

    // ---- CSR build (shared by GAT1, GAT2, HGT) ----
    hipMemsetAsync(tmpc, 0, 3*NN*sizeof(int), stream);
    hist_k<<<3*EE/256, 256, 0, stream>>>(eidx, tmpc);
    scan1_k<<<192, 256, 0, stream>>>(tmpc, coff, parts);
    scan2_k<<<1, 64, 0, stream>>>(parts);
    scan3_k<<<192, 256, 0, stream>>>(coff, parts);
    hipMemsetAsync(tmpc, 0, 3*NN*sizeof(int), stream);
    scatter_k<<<3*EE/256, 256, 0, stream>>>(eidx, coff, tmpc, csrc);

    // ---- FiLM small MLP (independent) ----
    int B = in_sizes[1] / 128;
    film_k<<<B, 256, 0, stream>>>(z_h, fW1, fb1, fW2, fb2, gbuf);

    // ---- GAT layer 1 ----
    gat_gemm3_k<<<1024, 256, 0, stream>>>(x_cell, g1W, g1as, g1ad, hb, alsb, aldb);
    gat_aggres_k<<<16384, 256, 0, stream>>>(hb, alsb, aldb, coff, csrc, g1b, x_cell, n1s, x1);

    // ---- GAT layer 2 ----
    gat_gemm3_k<<<1024, 256, 0, stream>>>(x1, g2W, g2as, g2ad, hb, alsb, aldb);
    gat_aggres_k<<<16384, 256, 0, stream>>>(hb, alsb, aldb, coff, csrc, g2b, x1, n2s, x2);

    // ---- HGT ----
    gemm_kqv_k<<<1024, 256, 0, stream>>>(x2, Wk, bk, Wq, bq, Wv, bv, kb, qb, vb);
    gemm_rel6_k<<<1024, 256, 0, stream>>>(kb, vb, arel, mrel, ktb, vtb);
    hgt_agg_k<<<16384, 256, 0, stream>>>(ktb, vtb, qb, prel, coff, csrc, aggb);
    gemm_wo_res_k<<<1024, 256, 0, stream>>>(aggb, Wo, bo, x2, skipp, n3s, outp);

    // ---- inject + FiLM apply ----
    gemm_inj_film_k<<<1024, 256, 0, stream>>>(x_emb, injW, injb, gbuf, bszp, outp);
}

// Round 3
// 800.234 us; speedup vs baseline: 1.9914x; 1.2401x over previous
//
#include <hip/hip_runtime.h>

#define NN 65536
#define EE 262144
#define ND ((size_t)NN * 128)
#define TBW 132

typedef unsigned short u16;
typedef short bf8_t __attribute__((ext_vector_type(8)));
typedef float f32x4 __attribute__((ext_vector_type(4)));

__device__ __forceinline__ float lrelu(float x){ return x > 0.f ? x : 0.2f*x; }
__device__ __forceinline__ float gelu_exact(float x){ return 0.5f*x*(1.f+erff(x*0.70710678118654752f)); }
__device__ __forceinline__ u16 f2bf(float f){
    union { float f; unsigned u; } v; v.f = f;
    unsigned u = v.u;
    return (u16)((u + 0x7FFFu + ((u >> 16) & 1u)) >> 16);
}
__device__ __forceinline__ float bf2f(u16 b){
    union { unsigned u; float f; } v; v.u = ((unsigned)b) << 16; return v.f;
}
__device__ __forceinline__ float2 bf2x(unsigned p){
    union { unsigned u; float f; } a, b;
    a.u = (p & 0xFFFFu) << 16; b.u = p & 0xFFFF0000u;
    return make_float2(a.f, b.f);
}
__device__ __forceinline__ unsigned cvt2(float a, float b){
    unsigned r; asm("v_cvt_pk_bf16_f32 %0, %1, %2" : "=v"(r) : "v"(a), "v"(b)); return r;
}

// ============ register-GEMM building blocks (no barriers) ============
// A-fragment: lane holds rows (rw+lr), k-slice kk*32+lk*8 .. +7
__device__ __forceinline__ void load_af32(const float* __restrict__ X, int row, int lk, bf8_t* af){
    #pragma unroll
    for (int kk = 0; kk < 4; ++kk){
        const float* p = X + (size_t)row*128 + kk*32 + lk*8;
        float4 a = *(const float4*)p;
        float4 b = *(const float4*)(p+4);
        union { bf8_t v; unsigned u[4]; } r;
        r.u[0] = cvt2(a.x, a.y); r.u[1] = cvt2(a.z, a.w);
        r.u[2] = cvt2(b.x, b.y); r.u[3] = cvt2(b.z, b.w);
        af[kk] = r.v;
    }
}
__device__ __forceinline__ void load_af16(const u16* __restrict__ X, int row, int lk, bf8_t* af){
    #pragma unroll
    for (int kk = 0; kk < 4; ++kk)
        af[kk] = *(const bf8_t*)(X + (size_t)row*128 + kk*32 + lk*8);
}
// C[64 rows x 128] via 32 MFMA; Wp is pre-transposed bf16 [n][k] (128x128)
__device__ __forceinline__ void mfma_w(const bf8_t* af, const u16* __restrict__ Wp,
                                       int lr, int lk, f32x4* acc){
    #pragma unroll
    for (int i = 0; i < 8; ++i) acc[i] = (f32x4){0.f,0.f,0.f,0.f};
    #pragma unroll
    for (int kk = 0; kk < 4; ++kk){
        #pragma unroll
        for (int nt = 0; nt < 8; ++nt){
            bf8_t b = *(const bf8_t*)&Wp[(nt*16+lr)*128 + kk*32 + lk*8];
            acc[nt] = __builtin_amdgcn_mfma_f32_16x16x32_bf16(af[kk], b, acc[nt], 0, 0, 0);
        }
    }
}
// wave-private transpose buffer: acc -> tb (bf16), then coalesced stores / A-frags
__device__ __forceinline__ void acc_to_tb(u16 (*tbw)[TBW], const f32x4* acc, int lr, int lk, const float* bias){
    asm volatile("s_waitcnt lgkmcnt(0)" ::: "memory");   // WAR: prior tb reads done
    #pragma unroll
    for (int nt = 0; nt < 8; ++nt){
        int col = nt*16 + lr;
        float badd = bias ? bias[col] : 0.f;
        #pragma unroll
        for (int i = 0; i < 4; ++i) tbw[lk*4+i][col] = f2bf(acc[nt][i] + badd);
    }
    asm volatile("s_waitcnt lgkmcnt(0)" ::: "memory");   // RAW: writes visible
}
__device__ __forceinline__ void tb_store(const u16 (*tbw)[TBW], u16* __restrict__ O, int rowbase, int lr, int lk){
    #pragma unroll
    for (int c = 0; c < 4; ++c){
        bf8_t v = *(const bf8_t*)&tbw[c*4+lk][lr*8];
        *(bf8_t*)(O + (size_t)(rowbase + c*4 + lk)*128 + lr*8) = v;
    }
}
__device__ __forceinline__ void tb_frags(const u16 (*tbw)[TBW], int lr, int lk, bf8_t* ha){
    #pragma unroll
    for (int kk = 0; kk < 4; ++kk) ha[kk] = *(const bf8_t*)&tbw[lr][kk*32 + lk*8];
}

// ============ weight pre-pack: f32 -> bf16, transposed to B-frag layout ============
__global__ __launch_bounds__(256) void wpack_k(
    const float* __restrict__ g1W, const float* __restrict__ g2W,
    const float* __restrict__ Wk, const float* __restrict__ Wq, const float* __restrict__ Wv,
    const float* __restrict__ Wo, const float* __restrict__ injW,
    const float* __restrict__ arel, const float* __restrict__ mrel,
    const float* __restrict__ g1as, const float* __restrict__ g1ad,
    const float* __restrict__ g2as, const float* __restrict__ g2ad,
    u16* __restrict__ wp, u16* __restrict__ wpa)
{
    int b = blockIdx.x, tid = threadIdx.x;
    if (b < 17) {
        const float* src; int rel = 0;
        if (b < 3) src = g1W + b*16384;
        else if (b < 6) src = g2W + (b-3)*16384;
        else if (b == 6) src = Wk;
        else if (b == 7) src = Wq;
        else if (b == 8) src = Wv;
        else if (b == 9) src = Wo;
        else if (b == 10) src = injW;
        else if (b < 14) { src = arel + (b-11)*4096; rel = 1; }
        else { src = mrel + (b-14)*4096; rel = 1; }
        u16* dst = wp + (size_t)b*16384;
        for (int idx = tid; idx < 16384; idx += 256) {
            int n = idx >> 7, k = idx & 127;
            float v;
            if (rel) v = ((n>>5)==(k>>5)) ? src[(n>>5)*1024 + (k&31)*32 + (n&31)] : 0.f;
            else v = src[k*128 + n];
            dst[idx] = f2bf(v);
        }
    } else {
        for (int idx = tid; idx < 6*2048; idx += 256) {
            int m = idx >> 11;
            int j = idx & 2047;
            int cg = j >> 7, k = j & 127;
            const float* as = (m < 3) ? g1as : g2as;
            const float* ad = (m < 3) ? g1ad : g2ad;
            int t = (m < 3) ? m : m - 3;
            float v = 0.f;
            if (cg < 4)      { if ((k>>5)==cg)   v = as[t*128 + cg*32 + (k&31)]; }
            else if (cg < 8) { int g = cg-4; if ((k>>5)==g) v = ad[t*128 + g*32 + (k&31)]; }
            wpa[idx] = f2bf(v);
        }
    }
}

// ============ GAT: 3 projections + fused alpha (via MFMA), bf16 h out ============
__global__ __launch_bounds__(256) void gat_gemm3_k(const float* __restrict__ X,
    const u16* __restrict__ wpg, const u16* __restrict__ wpa,
    u16* __restrict__ hb, float* __restrict__ alsb, float* __restrict__ aldb)
{
    __shared__ u16 tb[4][16][TBW];
    const int tid = threadIdx.x, wave = tid>>6, lane = tid&63, lr = lane&15, lk = lane>>4;
    const int rw = blockIdx.x*64 + wave*16;
    bf8_t af[4]; load_af32(X, rw + lr, lk, af);
    f32x4 acc[8]; bf8_t ha[4];
    for (int t = 0; t < 3; ++t) {
        mfma_w(af, wpg + t*16384, lr, lk, acc);
        acc_to_tb(tb[wave], acc, lr, lk, nullptr);
        tb_store(tb[wave], hb + (size_t)t*ND, rw, lr, lk);
        tb_frags(tb[wave], lr, lk, ha);
        f32x4 a2 = (f32x4){0.f,0.f,0.f,0.f};
        #pragma unroll
        for (int kk = 0; kk < 4; ++kk){
            bf8_t b = *(const bf8_t*)&wpa[t*2048 + lr*128 + kk*32 + lk*8];
            a2 = __builtin_amdgcn_mfma_f32_16x16x32_bf16(ha[kk], b, a2, 0, 0, 0);
        }
        if (lr < 8){
            float* dp = (lr < 4) ? alsb : aldb;
            int g = lr & 3;
            #pragma unroll
            for (int i = 0; i < 4; ++i)
                dp[((size_t)t*NN + rw + lk*4 + i)*4 + g] = a2[i];
        }
    }
}

// ============ HGT projections: k,q,v (+bias) and kt,vt (block-diag rel) ============
__global__ __launch_bounds__(256) void hgt_proj_k(const float* __restrict__ X,
    const u16* __restrict__ wpk, const u16* __restrict__ wpq, const u16* __restrict__ wpv,
    const u16* __restrict__ wparel, const u16* __restrict__ wpmrel,
    const float* __restrict__ bk, const float* __restrict__ bq, const float* __restrict__ bv,
    u16* __restrict__ kb, u16* __restrict__ qb, u16* __restrict__ vb,
    u16* __restrict__ ktb, u16* __restrict__ vtb)
{
    __shared__ u16 tb[4][16][TBW];
    const int tid = threadIdx.x, wave = tid>>6, lane = tid&63, lr = lane&15, lk = lane>>4;
    const int rw = blockIdx.x*64 + wave*16;
    bf8_t af[4]; load_af32(X, rw + lr, lk, af);
    f32x4 acc[8]; bf8_t ha[4];
    // k -> kb, then kt[t]
    mfma_w(af, wpk, lr, lk, acc);
    acc_to_tb(tb[wave], acc, lr, lk, bk);
    tb_store(tb[wave], kb, rw, lr, lk);
    tb_frags(tb[wave], lr, lk, ha);
    for (int t = 0; t < 3; ++t){
        mfma_w(ha, wparel + t*16384, lr, lk, acc);
        acc_to_tb(tb[wave], acc, lr, lk, nullptr);
        tb_store(tb[wave], ktb + (size_t)t*ND, rw, lr, lk);
    }
    // q -> qb
    mfma_w(af, wpq, lr, lk, acc);
    acc_to_tb(tb[wave], acc, lr, lk, bq);
    tb_store(tb[wave], qb, rw, lr, lk);
    // v -> vb, then vt[t]
    mfma_w(af, wpv, lr, lk, acc);
    acc_to_tb(tb[wave], acc, lr, lk, bv);
    tb_store(tb[wave], vb, rw, lr, lk);
    tb_frags(tb[wave], lr, lk, ha);
    for (int t = 0; t < 3; ++t){
        mfma_w(ha, wpmrel + t*16384, lr, lk, acc);
        acc_to_tb(tb[wave], acc, lr, lk, nullptr);
        tb_store(tb[wave], vtb + (size_t)t*ND, rw, lr, lk);
    }
}

// ============ final: Wo GEMM + HGT residual/rmsnorm + inject GEMM + FiLM ============
__global__ __launch_bounds__(256) void final_k(const u16* __restrict__ aggb,
    const u16* __restrict__ wpo, const float* __restrict__ bo,
    const float* __restrict__ x2, const float* __restrict__ skipp, const float* __restrict__ scale,
    const float* __restrict__ xemb, const u16* __restrict__ wpinj, const float* __restrict__ injb,
    const float* __restrict__ gbuf, const int* __restrict__ bszp,
    float* __restrict__ out)
{
    const int tid = threadIdx.x, wave = tid>>6, lane = tid&63, lr = lane&15, lk = lane>>4;
    const int rw = blockIdx.x*64 + wave*16;
    bf8_t afa[4]; load_af16(aggb, rw + lr, lk, afa);
    f32x4 acc[8]; mfma_w(afa, wpo, lr, lk, acc);
    const float sig = 1.f/(1.f + expf(-skipp[0]));
    float vv[8][4], xv[8][4], ss[4] = {0.f,0.f,0.f,0.f};
    #pragma unroll
    for (int nt = 0; nt < 8; ++nt){
        int col = nt*16 + lr;
        float badd = bo[col];
        #pragma unroll
        for (int i = 0; i < 4; ++i){
            float h = acc[nt][i] + badd;
            float x = x2[(size_t)(rw + lk*4 + i)*128 + col];
            float v = sig*h + (1.f - sig)*x;
            vv[nt][i] = v; xv[nt][i] = x;
            ss[i] += v*v;
        }
    }
    #pragma unroll
    for (int i = 0; i < 4; ++i){
        #pragma unroll
        for (int o = 1; o < 16; o <<= 1) ss[i] += __shfl_xor(ss[i], o);
    }
    float rr[4];
    #pragma unroll
    for (int i = 0; i < 4; ++i) rr[i] = rsqrtf(ss[i]*(1.f/128.f) + 1e-6f);
    #pragma unroll
    for (int nt = 0; nt < 8; ++nt){
        int col = nt*16 + lr;
        float sc = scale[col];
        #pragma unroll
        for (int i = 0; i < 4; ++i)
            vv[nt][i] = lrelu(xv[nt][i] + sc*vv[nt][i]*rr[i]);   // = x3 (pre-inject)
    }
    bf8_t af2[4]; load_af32(xemb, rw + lr, lk, af2);
    f32x4 acc2[8]; mfma_w(af2, wpinj, lr, lk, acc2);
    const int cpb = NN / *bszp;
    #pragma unroll
    for (int i = 0; i < 4; ++i){
        int row = rw + lk*4 + i;
        const float* gr = gbuf + (row / cpb)*256;
        #pragma unroll
        for (int nt = 0; nt < 8; ++nt){
            int col = nt*16 + lr;
            float h = vv[nt][i] + acc2[nt][i] + injb[col];
            out[(size_t)row*128 + col] = (1.f + gr[col])*h + gr[128 + col];
        }
    }
}

// ================= CSR build =================
__global__ __launch_bounds__(256) void hist_k(const int* __restrict__ ei, int* __restrict__ cnt){
    int gid = blockIdx.x*256 + threadIdx.x;
    int t = gid / EE, e = gid - t*EE;
    int d = ei[t*2*EE + EE + e];
    atomicAdd(&cnt[t*NN + d], 1);
}
__global__ __launch_bounds__(256) void scan1_k(const int* __restrict__ cnt, int* __restrict__ off, int* __restrict__ parts){
    __shared__ int sums[256];
    int b = blockIdx.x; int t = b >> 6; int base = (b & 63) * 1024;
    int tid = threadIdx.x;
    int v[4]; int tsum = 0;
    int gbase = t*NN + base + tid*4;
    #pragma unroll
    for (int i = 0; i < 4; ++i){ v[i] = cnt[gbase+i]; tsum += v[i]; }
    sums[tid] = tsum; __syncthreads();
    for (int ofs = 1; ofs < 256; ofs <<= 1) {
        int a = (tid >= ofs) ? sums[tid-ofs] : 0;
        __syncthreads();
        sums[tid] += a;
        __syncthreads();
    }
    int run = sums[tid] - tsum;
    int obase = t*(NN+1) + base + tid*4;
    #pragma unroll
    for (int i = 0; i < 4; ++i){ off[obase+i] = run; run += v[i]; }
    if (tid == 255) parts[b] = sums[255];
}
__global__ void scan2_k(int* parts){
    if (threadIdx.x == 0 && blockIdx.x == 0) {
        for (int t = 0; t < 3; ++t) {
            int run = 0;
            for (int i = 0; i < 64; ++i) { int b = t*64+i; int v = parts[b]; parts[b] = run; run += v; }
        }
    }
}
__global__ __launch_bounds__(256) void scan3_k(int* __restrict__ off, const int* __restrict__ parts){
    int b = blockIdx.x; int t = b >> 6; int base = (b & 63) * 1024;
    int add = parts[b];
    int idx = t*(NN+1) + base + threadIdx.x*4;
    #pragma unroll
    for (int i = 0; i < 4; ++i) off[idx+i] += add;
    if (threadIdx.x == 0 && (b & 63) == 0) off[t*(NN+1) + NN] = EE;
}
__global__ __launch_bounds__(256) void scatter_k(const int* __restrict__ ei, const int* __restrict__ off,
                                                 int* __restrict__ cur, int* __restrict__ out){
    int gid = blockIdx.x*256 + threadIdx.x;
    int t = gid / EE, e = gid - t*EE;
    int s = ei[t*2*EE + e];
    int d = ei[t*2*EE + EE + e];
    int p = atomicAdd(&cur[t*NN + d], 1);
    out[t*EE + off[t*(NN+1)+d] + p] = s;
}

// ============ fused GAT aggregate (3 types) + bias + rmsnorm residual ============
__global__ __launch_bounds__(256) void gat_aggres_k(const u16* __restrict__ hb,
    const float* __restrict__ alsb, const float* __restrict__ aldb,
    const int* __restrict__ coff, const int* __restrict__ csrc,
    const float* __restrict__ bias3, const float* __restrict__ xold,
    const float* __restrict__ scale, float* __restrict__ out)
{
    int gid = blockIdx.x*256 + threadIdx.x;
    int node = gid >> 6, lane = gid & 63;
    int g = lane >> 4;
    float a0 = 0.f, a1 = 0.f;
    for (int t = 0; t < 3; ++t) {
        const u16* h = hb + (size_t)t*ND;
        const float* als = alsb + (size_t)t*NN*4;
        float ad = aldb[(size_t)t*NN*4 + node*4 + g];
        float aself = als[node*4 + g];
        int beg = coff[t*(NN+1) + node], end = coff[t*(NN+1) + node + 1];
        float ex = expf(lrelu(aself + ad));
        float dsum = ex;
        float2 hv = bf2x(*(const unsigned*)&h[(size_t)node*128 + lane*2]);
        float s0 = ex*hv.x, s1 = ex*hv.y;
        for (int e = beg; e < end; ++e) {
            int s = csrc[t*EE + e];
            float exx = expf(lrelu(als[s*4 + g] + ad));
            float2 hw = bf2x(*(const unsigned*)&h[(size_t)s*128 + lane*2]);
            dsum += exx; s0 += exx*hw.x; s1 += exx*hw.y;
        }
        float inv = 1.f/(dsum + 1e-16f);
        a0 += s0*inv; a1 += s1*inv;
    }
    int c0 = lane*2;
    a0 += bias3[c0]   + bias3[128+c0]   + bias3[256+c0];
    a1 += bias3[c0+1] + bias3[128+c0+1] + bias3[256+c0+1];
    float ssum = a0*a0 + a1*a1;
    #pragma unroll
    for (int o = 1; o < 64; o <<= 1) ssum += __shfl_xor(ssum, o);
    float r = rsqrtf(ssum*(1.f/128.f) + 1e-6f);
    size_t off = (size_t)node*128 + c0;
    float2 xo = *(const float2*)&xold[off];
    out[off]   = lrelu(xo.x + scale[c0]*a0*r);
    out[off+1] = lrelu(xo.y + scale[c0+1]*a1*r);
}

// ============ HGT aggregate (joint softmax over 3 types) + gelu, bf16 out ============
__global__ __launch_bounds__(256) void hgt_agg_k(const u16* __restrict__ ktb,
    const u16* __restrict__ vtb, const u16* __restrict__ qb,
    const float* __restrict__ prel, const int* __restrict__ coff,
    const int* __restrict__ csrc, u16* __restrict__ aggb)
{
    int gid = blockIdx.x*256 + threadIdx.x;
    int node = gid >> 6, lane = gid & 63;
    int hh = lane >> 4;
    float2 qv = bf2x(*(const unsigned*)&qb[(size_t)node*128 + lane*2]);
    float dsum = 0.f, a0 = 0.f, a1 = 0.f;
    for (int t = 0; t < 3; ++t) {
        float ph = prel[t*4 + hh] * 0.17677669529663689f;  // 1/sqrt(32)
        int beg = coff[t*(NN+1) + node], end = coff[t*(NN+1) + node + 1];
        const u16* kt = ktb + (size_t)t*ND;
        const u16* vt = vtb + (size_t)t*ND;
        for (int e = beg; e < end; ++e) {
            int s = csrc[t*EE + e];
            size_t ro = (size_t)s*128 + lane*2;
            float2 kv = bf2x(*(const unsigned*)&kt[ro]);
            float sc = qv.x*kv.x + qv.y*kv.y;
            #pragma unroll
            for (int o = 1; o < 16; o <<= 1) sc += __shfl_xor(sc, o);
            float ex = expf(sc * ph);
            float2 vx = bf2x(*(const unsigned*)&vt[ro]);
            dsum += ex; a0 += ex*vx.x; a1 += ex*vx.y;
        }
    }
    float inv = 1.f/(dsum + 1e-16f);
    size_t o = (size_t)node*128 + lane*2;
    aggb[o]   = f2bf(gelu_exact(a0*inv));
    aggb[o+1] = f2bf(gelu_exact(a1*inv));
}

// ============ FiLM small MLP: one block per batch row ============
__global__ __launch_bounds__(256) void film_k(const float* __restrict__ z,
    const float* __restrict__ W1, const float* __restrict__ b1,
    const float* __restrict__ W2, const float* __restrict__ b2,
    float* __restrict__ gb)
{
    __shared__ float zr[128];
    __shared__ float g1[256];
    int r = blockIdx.x, tid = threadIdx.x;
    if (tid < 128) zr[tid] = z[r*128 + tid];
    __syncthreads();
    float s = b1[tid];
    for (int k = 0; k < 128; ++k) s += zr[k]*W1[k*256 + tid];
    g1[tid] = gelu_exact(s);
    __syncthreads();
    float s2 = b2[tid];
    for (int k = 0; k < 256; ++k) s2 += g1[k]*W2[k*256 + tid];
    gb[r*256 + tid] = 0.1f*tanhf(s2);
}

// ================= launch =================
extern "C" void kernel_launch(void* const* d_in, const int* in_sizes, int n_in,
                              void* d_out, int out_size, void* d_ws, size_t ws_size,
                              hipStream_t stream)
{
    const float* x_cell = (const float*)d_in[0];
    const float* z_h    = (const float*)d_in[1];
    const float* x_emb  = (const float*)d_in[2];
    const int*   eidx   = (const int*)d_in[3];
    const int*   bszp   = (const int*)d_in[4];
    const float* g1W  = (const float*)d_in[5];
    const float* g1as = (const float*)d_in[6];
    const float* g1ad = (const float*)d_in[7];
    const float* g1b  = (const float*)d_in[8];
    const float* g2W  = (const float*)d_in[9];
    const float* g2as = (const float*)d_in[10];
    const float* g2ad = (const float*)d_in[11];
    const float* g2b  = (const float*)d_in[12];
    const float* n1s  = (const float*)d_in[13];
    const float* n2s  = (const float*)d_in[14];
    const float* n3s  = (const float*)d_in[15];
    const float* Wk   = (const float*)d_in[16];
    const float* bk   = (const float*)d_in[17];
    const float* Wq   = (const float*)d_in[18];
    const float* bq   = (const float*)d_in[19];
    const float* Wv   = (const float*)d_in[20];
    const float* bv   = (const float*)d_in[21];
    const float* arel = (const float*)d_in[22];
    const float* mrel = (const float*)d_in[23];
    const float* prel = (const float*)d_in[24];
    const float* Wo   = (const float*)d_in[25];
    const float* bo   = (const float*)d_in[26];
    const float* skipp= (const float*)d_in[27];
    const float* injW = (const float*)d_in[28];
    const float* injb = (const float*)d_in[29];
    const float* fW1  = (const float*)d_in[30];
    const float* fb1  = (const float*)d_in[31];
    const float* fW2  = (const float*)d_in[32];
    const float* fb2  = (const float*)d_in[33];

    // ---- workspace layout ----
    u16* wp   = (u16*)d_ws;                  // 17 * 16384 u16
    u16* wpa  = wp + (size_t)17*16384;       // 6 * 2048 u16
    float* x2   = (float*)(wpa + 6*2048);    // ND f32
    float* alsb = x2 + ND;                   // 3*NN*4
    float* aldb = alsb + (size_t)3*NN*4;     // 3*NN*4
    float* gbuf = aldb + (size_t)3*NN*4;     // 32*256
    int* coff   = (int*)(gbuf + 32*256);     // 3*(NN+1)
    int* csrc   = coff + 3*(NN+1);           // 3*EE
    int* tmpc   = csrc + 3*EE;               // 3*NN
    int* parts  = tmpc + 3*NN;               // 256
    u16* R1     = (u16*)(parts + 256);       // 3*ND u16
    u16* R2     = R1 + 3*ND;                 // 6*ND u16

    u16* hb  = R1;
    u16* kb  = R1;
    u16* qb  = R1 + ND;
    u16* vb  = R1 + 2*ND;
    u16* ktb = R2;
    u16* vtb = R2 + 3*ND;
    u16* aggb = R1;                          // reuse k slot (dead after proj)
    float* x1   = (float*)d_out;
    float* outp = (float*)d_out;

    const u16* wpg1 = wp;
    const u16* wpg2 = wp + (size_t)3*16384;
    const u16* wpk  = wp + (size_t)6*16384;
    const u16* wpq  = wp + (size_t)7*16384;
    const u16* wpv  = wp + (size_t)8*16384;
    const u16* wpo  = wp + (size_t)9*16384;
    const u16* wpinj= wp + (size_t)10*16384;
    const u16* wparel = wp + (size_t)11*16384;
    const u16* wpmrel = wp + (size_t)14*16384;

    // ---- weight pre-pack ----
    wpack_k<<<18, 256, 0, stream>>>(g1W, g2W, Wk, Wq, Wv, Wo, injW, arel, mrel,
                                    g1as, g1ad, g2as, g2ad, wp, wpa);

    // ---- CSR build (shared by GAT1, GAT2, HGT) ----
    hipMemsetAsync(tmpc, 0, 3*NN*sizeof(int), stream);
    hist_k<<<3*EE/256, 256, 0, stream>>>(eidx, tmpc);
    scan1_k<<<192, 256, 0, stream>>>(tmpc, coff, parts);
    scan2_k<<<1, 64, 0, stream>>>(parts);
    scan3_k<<<192, 256, 0, stream>>>(coff, parts);
    hipMemsetAsync(tmpc, 0, 3*NN*sizeof(int), stream);
    scatter_k<<<3*EE/256, 256, 0, stream>>>(eidx, coff, tmpc, csrc);

    // ---- FiLM small MLP ----
    int B = in_sizes[1] / 128;
    film_k<<<B, 256, 0, stream>>>(z_h, fW1, fb1, fW2, fb2, gbuf);

    // ---- GAT layer 1 ----
    gat_gemm3_k<<<1024, 256, 0, stream>>>(x_cell, wpg1, wpa, hb, alsb, aldb);
    gat_aggres_k<<<16384, 256, 0, stream>>>(hb, alsb, aldb, coff, csrc, g1b, x_cell, n1s, x1);

    // ---- GAT layer 2 ----
    gat_gemm3_k<<<1024, 256, 0, stream>>>(x1, wpg2, wpa + 3*2048, hb, alsb, aldb);
    gat_aggres_k<<<16384, 256, 0, stream>>>(hb, alsb, aldb, coff, csrc, g2b, x1, n2s, x2);

    // ---- HGT ----
    hgt_proj_k<<<1024, 256, 0, stream>>>(x2, wpk, wpq, wpv, wparel, wpmrel,
                                         bk, bq, bv, kb, qb, vb, ktb, vtb);
    hgt_agg_k<<<16384, 256, 0, stream>>>(ktb, vtb, qb, prel, coff, csrc, aggb);

    // ---- final: Wo + residual + inject + FiLM ----
    final_k<<<1024, 256, 0, stream>>>(aggb, wpo, bo, x2, skipp, n3s,
                                      x_emb, wpinj, injb, gbuf, bszp, outp);
}

// Round 4
// 666.226 us; speedup vs baseline: 2.3920x; 1.2011x over previous
//
#include <hip/hip_runtime.h>

#define NN 65536
#define EE 262144
#define ND ((size_t)NN * 128)
#define TBW 132

typedef unsigned short u16;
typedef short bf8_t __attribute__((ext_vector_type(8)));
typedef float f32x4 __attribute__((ext_vector_type(4)));

__device__ __forceinline__ float lrelu(float x){ return x > 0.f ? x : 0.2f*x; }
__device__ __forceinline__ float gelu_exact(float x){ return 0.5f*x*(1.f+erff(x*0.70710678118654752f)); }
__device__ __forceinline__ u16 f2bf(float f){
    union { float f; unsigned u; } v; v.f = f;
    unsigned u = v.u;
    return (u16)((u + 0x7FFFu + ((u >> 16) & 1u)) >> 16);
}
__device__ __forceinline__ float bf2f(u16 b){
    union { unsigned u; float f; } v; v.u = ((unsigned)b) << 16; return v.f;
}
__device__ __forceinline__ float2 bf2x(unsigned p){
    union { unsigned u; float f; } a, b;
    a.u = (p & 0xFFFFu) << 16; b.u = p & 0xFFFF0000u;
    return make_float2(a.f, b.f);
}
__device__ __forceinline__ unsigned cvt2(float a, float b){
    unsigned r; asm("v_cvt_pk_bf16_f32 %0, %1, %2" : "=v"(r) : "v"(a), "v"(b)); return r;
}

// ============ register-GEMM building blocks (no barriers) ============
__device__ __forceinline__ void load_af32(const float* __restrict__ X, int row, int lk, bf8_t* af){
    #pragma unroll
    for (int kk = 0; kk < 4; ++kk){
        const float* p = X + (size_t)row*128 + kk*32 + lk*8;
        float4 a = *(const float4*)p;
        float4 b = *(const float4*)(p+4);
        union { bf8_t v; unsigned u[4]; } r;
        r.u[0] = cvt2(a.x, a.y); r.u[1] = cvt2(a.z, a.w);
        r.u[2] = cvt2(b.x, b.y); r.u[3] = cvt2(b.z, b.w);
        af[kk] = r.v;
    }
}
__device__ __forceinline__ void load_af16(const u16* __restrict__ X, int row, int lk, bf8_t* af){
    #pragma unroll
    for (int kk = 0; kk < 4; ++kk)
        af[kk] = *(const bf8_t*)(X + (size_t)row*128 + kk*32 + lk*8);
}
// 1-tile GEMM, batched B loads (8 loads then 8 MFMAs per k-slice)
__device__ __forceinline__ void mfma_w1(const bf8_t* af, const u16* __restrict__ Wp,
                                        int lr, int lk, f32x4* acc){
    #pragma unroll
    for (int i = 0; i < 8; ++i) acc[i] = (f32x4){0.f,0.f,0.f,0.f};
    #pragma unroll
    for (int kk = 0; kk < 4; ++kk){
        bf8_t B[8];
        #pragma unroll
        for (int nt = 0; nt < 8; ++nt)
            B[nt] = *(const bf8_t*)&Wp[(nt*16+lr)*128 + kk*32 + lk*8];
        #pragma unroll
        for (int nt = 0; nt < 8; ++nt)
            acc[nt] = __builtin_amdgcn_mfma_f32_16x16x32_bf16(af[kk], B[nt], acc[nt], 0, 0, 0);
    }
}
// 2-tile GEMM sharing B fragments
__device__ __forceinline__ void mfma_w2(const bf8_t* af0, const bf8_t* af1,
                                        const u16* __restrict__ Wp,
                                        int lr, int lk, f32x4* acc0, f32x4* acc1){
    #pragma unroll
    for (int i = 0; i < 8; ++i){ acc0[i] = (f32x4){0.f,0.f,0.f,0.f}; acc1[i] = (f32x4){0.f,0.f,0.f,0.f}; }
    #pragma unroll
    for (int kk = 0; kk < 4; ++kk){
        bf8_t B[8];
        #pragma unroll
        for (int nt = 0; nt < 8; ++nt)
            B[nt] = *(const bf8_t*)&Wp[(nt*16+lr)*128 + kk*32 + lk*8];
        #pragma unroll
        for (int nt = 0; nt < 8; ++nt){
            acc0[nt] = __builtin_amdgcn_mfma_f32_16x16x32_bf16(af0[kk], B[nt], acc0[nt], 0, 0, 0);
            acc1[nt] = __builtin_amdgcn_mfma_f32_16x16x32_bf16(af1[kk], B[nt], acc1[nt], 0, 0, 0);
        }
    }
}
// wave-private transpose buffer: acc -> tb (bf16), then coalesced stores / A-frags
__device__ __forceinline__ void acc_to_tb(u16 (*tbw)[TBW], const f32x4* acc, int lr, int lk, const float* bias){
    asm volatile("s_waitcnt lgkmcnt(0)" ::: "memory");   // WAR: prior tb reads done
    #pragma unroll
    for (int nt = 0; nt < 8; ++nt){
        int col = nt*16 + lr;
        float badd = bias ? bias[col] : 0.f;
        #pragma unroll
        for (int i = 0; i < 4; ++i) tbw[lk*4+i][col] = f2bf(acc[nt][i] + badd);
    }
    asm volatile("s_waitcnt lgkmcnt(0)" ::: "memory");   // RAW: writes visible
}
__device__ __forceinline__ void tb_store(const u16 (*tbw)[TBW], u16* __restrict__ O, int rowbase, int lr, int lk){
    #pragma unroll
    for (int c = 0; c < 4; ++c){
        bf8_t v = *(const bf8_t*)&tbw[c*4+lk][lr*8];
        *(bf8_t*)(O + (size_t)(rowbase + c*4 + lk)*128 + lr*8) = v;
    }
}
__device__ __forceinline__ void tb_frags(const u16 (*tbw)[TBW], int lr, int lk, bf8_t* ha){
    #pragma unroll
    for (int kk = 0; kk < 4; ++kk) ha[kk] = *(const bf8_t*)&tbw[lr][kk*32 + lk*8];
}

// ============ weight pre-pack: f32 -> bf16, transposed to B-frag layout ============
__global__ __launch_bounds__(256) void wpack_k(
    const float* __restrict__ g1W, const float* __restrict__ g2W,
    const float* __restrict__ Wk, const float* __restrict__ Wq, const float* __restrict__ Wv,
    const float* __restrict__ Wo, const float* __restrict__ injW,
    const float* __restrict__ arel, const float* __restrict__ mrel,
    const float* __restrict__ g1as, const float* __restrict__ g1ad,
    const float* __restrict__ g2as, const float* __restrict__ g2ad,
    u16* __restrict__ wp, u16* __restrict__ wpa)
{
    int b = blockIdx.x, tid = threadIdx.x;
    if (b < 17) {
        const float* src; int rel = 0;
        if (b < 3) src = g1W + b*16384;
        else if (b < 6) src = g2W + (b-3)*16384;
        else if (b == 6) src = Wk;
        else if (b == 7) src = Wq;
        else if (b == 8) src = Wv;
        else if (b == 9) src = Wo;
        else if (b == 10) src = injW;
        else if (b < 14) { src = arel + (b-11)*4096; rel = 1; }
        else { src = mrel + (b-14)*4096; rel = 1; }
        u16* dst = wp + (size_t)b*16384;
        for (int idx = tid; idx < 16384; idx += 256) {
            int n = idx >> 7, k = idx & 127;
            float v;
            if (rel) v = ((n>>5)==(k>>5)) ? src[(n>>5)*1024 + (k&31)*32 + (n&31)] : 0.f;
            else v = src[k*128 + n];
            dst[idx] = f2bf(v);
        }
    } else {
        for (int idx = tid; idx < 6*2048; idx += 256) {
            int m = idx >> 11;
            int j = idx & 2047;
            int cg = j >> 7, k = j & 127;
            const float* as = (m < 3) ? g1as : g2as;
            const float* ad = (m < 3) ? g1ad : g2ad;
            int t = (m < 3) ? m : m - 3;
            float v = 0.f;
            if (cg < 4)      { if ((k>>5)==cg)   v = as[t*128 + cg*32 + (k&31)]; }
            else if (cg < 8) { int g = cg-4; if ((k>>5)==g) v = ad[t*128 + g*32 + (k&31)]; }
            wpa[idx] = f2bf(v);
        }
    }
}

// ============ GAT: 3 projections + fused alpha (via MFMA), 2 tiles/wave ============
__global__ __launch_bounds__(256, 2) void gat_gemm3_k(const float* __restrict__ X,
    const u16* __restrict__ wpg, const u16* __restrict__ wpa,
    u16* __restrict__ hb, float* __restrict__ alsb, float* __restrict__ aldb)
{
    __shared__ u16 tb[4][16][TBW];
    const int tid = threadIdx.x, wave = tid>>6, lane = tid&63, lr = lane&15, lk = lane>>4;
    const int rw0 = blockIdx.x*128 + wave*32;      // tile0 rows rw0.., tile1 rows rw0+16..
    bf8_t af0[4], af1[4];
    load_af32(X, rw0 + lr, lk, af0);
    load_af32(X, rw0 + 16 + lr, lk, af1);
    f32x4 acc0[8], acc1[8];
    for (int t = 0; t < 3; ++t) {
        mfma_w2(af0, af1, wpg + t*16384, lr, lk, acc0, acc1);
        bf8_t Ba[4];
        #pragma unroll
        for (int kk = 0; kk < 4; ++kk)
            Ba[kk] = *(const bf8_t*)&wpa[t*2048 + lr*128 + kk*32 + lk*8];
        u16* h = hb + (size_t)t*ND;
        float* alst = alsb + (size_t)t*NN*4;
        float* aldt = aldb + (size_t)t*NN*4;
        // ---- tile 0 ----
        {
            acc_to_tb(tb[wave], acc0, lr, lk, nullptr);
            tb_store(tb[wave], h, rw0, lr, lk);
            bf8_t ha[4]; tb_frags(tb[wave], lr, lk, ha);
            f32x4 a2 = (f32x4){0.f,0.f,0.f,0.f};
            #pragma unroll
            for (int kk = 0; kk < 4; ++kk)
                a2 = __builtin_amdgcn_mfma_f32_16x16x32_bf16(ha[kk], Ba[kk], a2, 0, 0, 0);
            if (lr < 8){
                float* dp = (lr < 4) ? alst : aldt;
                int g = lr & 3;
                #pragma unroll
                for (int i = 0; i < 4; ++i) dp[(size_t)(rw0 + lk*4 + i)*4 + g] = a2[i];
            }
        }
        // ---- tile 1 ----
        {
            acc_to_tb(tb[wave], acc1, lr, lk, nullptr);
            tb_store(tb[wave], h, rw0 + 16, lr, lk);
            bf8_t ha[4]; tb_frags(tb[wave], lr, lk, ha);
            f32x4 a2 = (f32x4){0.f,0.f,0.f,0.f};
            #pragma unroll
            for (int kk = 0; kk < 4; ++kk)
                a2 = __builtin_amdgcn_mfma_f32_16x16x32_bf16(ha[kk], Ba[kk], a2, 0, 0, 0);
            if (lr < 8){
                float* dp = (lr < 4) ? alst : aldt;
                int g = lr & 3;
                #pragma unroll
                for (int i = 0; i < 4; ++i) dp[(size_t)(rw0 + 16 + lk*4 + i)*4 + g] = a2[i];
            }
        }
    }
}

// ============ HGT projections: q (+bias) stored; kt,vt via in-register k,v ============
__global__ __launch_bounds__(256, 2) void hgt_proj_k(const float* __restrict__ X,
    const u16* __restrict__ wpk, const u16* __restrict__ wpq, const u16* __restrict__ wpv,
    const u16* __restrict__ wparel, const u16* __restrict__ wpmrel,
    const float* __restrict__ bk, const float* __restrict__ bq, const float* __restrict__ bv,
    u16* __restrict__ qb, u16* __restrict__ ktb, u16* __restrict__ vtb)
{
    __shared__ u16 tb[4][16][TBW];
    const int tid = threadIdx.x, wave = tid>>6, lane = tid&63, lr = lane&15, lk = lane>>4;
    const int rw0 = blockIdx.x*128 + wave*32;
    bf8_t af0[4], af1[4];
    load_af32(X, rw0 + lr, lk, af0);
    load_af32(X, rw0 + 16 + lr, lk, af1);
    f32x4 acc0[8], acc1[8];
    bf8_t ha0[4], ha1[4];
    // ---- k (not stored) -> frags ----
    mfma_w2(af0, af1, wpk, lr, lk, acc0, acc1);
    acc_to_tb(tb[wave], acc0, lr, lk, bk); tb_frags(tb[wave], lr, lk, ha0);
    acc_to_tb(tb[wave], acc1, lr, lk, bk); tb_frags(tb[wave], lr, lk, ha1);
    // ---- kt[t] ----
    for (int t = 0; t < 3; ++t){
        mfma_w2(ha0, ha1, wparel + t*16384, lr, lk, acc0, acc1);
        u16* o = ktb + (size_t)t*ND;
        acc_to_tb(tb[wave], acc0, lr, lk, nullptr); tb_store(tb[wave], o, rw0, lr, lk);
        acc_to_tb(tb[wave], acc1, lr, lk, nullptr); tb_store(tb[wave], o, rw0 + 16, lr, lk);
    }
    // ---- q -> qb ----
    mfma_w2(af0, af1, wpq, lr, lk, acc0, acc1);
    acc_to_tb(tb[wave], acc0, lr, lk, bq); tb_store(tb[wave], qb, rw0, lr, lk);
    acc_to_tb(tb[wave], acc1, lr, lk, bq); tb_store(tb[wave], qb, rw0 + 16, lr, lk);
    // ---- v (not stored) -> frags ----
    mfma_w2(af0, af1, wpv, lr, lk, acc0, acc1);
    acc_to_tb(tb[wave], acc0, lr, lk, bv); tb_frags(tb[wave], lr, lk, ha0);
    acc_to_tb(tb[wave], acc1, lr, lk, bv); tb_frags(tb[wave], lr, lk, ha1);
    // ---- vt[t] ----
    for (int t = 0; t < 3; ++t){
        mfma_w2(ha0, ha1, wpmrel + t*16384, lr, lk, acc0, acc1);
        u16* o = vtb + (size_t)t*ND;
        acc_to_tb(tb[wave], acc0, lr, lk, nullptr); tb_store(tb[wave], o, rw0, lr, lk);
        acc_to_tb(tb[wave], acc1, lr, lk, nullptr); tb_store(tb[wave], o, rw0 + 16, lr, lk);
    }
}

// ============ final: Wo GEMM + HGT residual/rmsnorm + inject GEMM + FiLM ============
__global__ __launch_bounds__(256) void final_k(const u16* __restrict__ aggb,
    const u16* __restrict__ wpo, const float* __restrict__ bo,
    const float* __restrict__ x2, const float* __restrict__ skipp, const float* __restrict__ scale,
    const float* __restrict__ xemb, const u16* __restrict__ wpinj, const float* __restrict__ injb,
    const float* __restrict__ gbuf, const int* __restrict__ bszp,
    float* __restrict__ out)
{
    const int tid = threadIdx.x, wave = tid>>6, lane = tid&63, lr = lane&15, lk = lane>>4;
    const int rw = blockIdx.x*64 + wave*16;
    bf8_t afa[4]; load_af16(aggb, rw + lr, lk, afa);
    f32x4 acc[8]; mfma_w1(afa, wpo, lr, lk, acc);
    const float sig = 1.f/(1.f + expf(-skipp[0]));
    float vv[8][4], xv[8][4], ss[4] = {0.f,0.f,0.f,0.f};
    #pragma unroll
    for (int nt = 0; nt < 8; ++nt){
        int col = nt*16 + lr;
        float badd = bo[col];
        #pragma unroll
        for (int i = 0; i < 4; ++i){
            float h = acc[nt][i] + badd;
            float x = x2[(size_t)(rw + lk*4 + i)*128 + col];
            float v = sig*h + (1.f - sig)*x;
            vv[nt][i] = v; xv[nt][i] = x;
            ss[i] += v*v;
        }
    }
    #pragma unroll
    for (int i = 0; i < 4; ++i){
        #pragma unroll
        for (int o = 1; o < 16; o <<= 1) ss[i] += __shfl_xor(ss[i], o);
    }
    float rr[4];
    #pragma unroll
    for (int i = 0; i < 4; ++i) rr[i] = rsqrtf(ss[i]*(1.f/128.f) + 1e-6f);
    #pragma unroll
    for (int nt = 0; nt < 8; ++nt){
        int col = nt*16 + lr;
        float sc = scale[col];
        #pragma unroll
        for (int i = 0; i < 4; ++i)
            vv[nt][i] = lrelu(xv[nt][i] + sc*vv[nt][i]*rr[i]);   // = x3 (pre-inject)
    }
    bf8_t af2[4]; load_af32(xemb, rw + lr, lk, af2);
    f32x4 acc2[8]; mfma_w1(af2, wpinj, lr, lk, acc2);
    const int cpb = NN / *bszp;
    #pragma unroll
    for (int i = 0; i < 4; ++i){
        int row = rw + lk*4 + i;
        const float* gr = gbuf + (row / cpb)*256;
        #pragma unroll
        for (int nt = 0; nt < 8; ++nt){
            int col = nt*16 + lr;
            float h = vv[nt][i] + acc2[nt][i] + injb[col];
            out[(size_t)row*128 + col] = (1.f + gr[col])*h + gr[128 + col];
        }
    }
}

// ================= CSR build =================
__global__ __launch_bounds__(256) void hist_k(const int* __restrict__ ei, int* __restrict__ cnt){
    int gid = blockIdx.x*256 + threadIdx.x;
    int t = gid / EE, e = gid - t*EE;
    int d = ei[t*2*EE + EE + e];
    atomicAdd(&cnt[t*NN + d], 1);
}
__global__ __launch_bounds__(256) void scan1_k(const int* __restrict__ cnt, int* __restrict__ off, int* __restrict__ parts){
    __shared__ int sums[256];
    int b = blockIdx.x; int t = b >> 6; int base = (b & 63) * 1024;
    int tid = threadIdx.x;
    int v[4]; int tsum = 0;
    int gbase = t*NN + base + tid*4;
    #pragma unroll
    for (int i = 0; i < 4; ++i){ v[i] = cnt[gbase+i]; tsum += v[i]; }
    sums[tid] = tsum; __syncthreads();
    for (int ofs = 1; ofs < 256; ofs <<= 1) {
        int a = (tid >= ofs) ? sums[tid-ofs] : 0;
        __syncthreads();
        sums[tid] += a;
        __syncthreads();
    }
    int run = sums[tid] - tsum;
    int obase = t*(NN+1) + base + tid*4;
    #pragma unroll
    for (int i = 0; i < 4; ++i){ off[obase+i] = run; run += v[i]; }
    if (tid == 255) parts[b] = sums[255];
}
__global__ void scan2_k(int* parts){
    if (threadIdx.x == 0 && blockIdx.x == 0) {
        for (int t = 0; t < 3; ++t) {
            int run = 0;
            for (int i = 0; i < 64; ++i) { int b = t*64+i; int v = parts[b]; parts[b] = run; run += v; }
        }
    }
}
__global__ __launch_bounds__(256) void scan3_k(int* __restrict__ off, const int* __restrict__ parts){
    int b = blockIdx.x; int t = b >> 6; int base = (b & 63) * 1024;
    int add = parts[b];
    int idx = t*(NN+1) + base + threadIdx.x*4;
    #pragma unroll
    for (int i = 0; i < 4; ++i) off[idx+i] += add;
    if (threadIdx.x == 0 && (b & 63) == 0) off[t*(NN+1) + NN] = EE;
}
__global__ __launch_bounds__(256) void scatter_k(const int* __restrict__ ei, const int* __restrict__ off,
                                                 int* __restrict__ cur, int* __restrict__ out){
    int gid = blockIdx.x*256 + threadIdx.x;
    int t = gid / EE, e = gid - t*EE;
    int s = ei[t*2*EE + e];
    int d = ei[t*2*EE + EE + e];
    int p = atomicAdd(&cur[t*NN + d], 1);
    out[t*EE + off[t*(NN+1)+d] + p] = s;
}

// ============ fused GAT aggregate (3 types) + bias + rmsnorm residual ============
__global__ __launch_bounds__(256) void gat_aggres_k(const u16* __restrict__ hb,
    const float* __restrict__ alsb, const float* __restrict__ aldb,
    const int* __restrict__ coff, const int* __restrict__ csrc,
    const float* __restrict__ bias3, const float* __restrict__ xold,
    const float* __restrict__ scale, float* __restrict__ out)
{
    int gid = blockIdx.x*256 + threadIdx.x;
    int node = gid >> 6, lane = gid & 63;
    int g = lane >> 4;
    float a0 = 0.f, a1 = 0.f;
    for (int t = 0; t < 3; ++t) {
        const u16* h = hb + (size_t)t*ND;
        const float* als = alsb + (size_t)t*NN*4;
        float ad = aldb[(size_t)t*NN*4 + node*4 + g];
        float aself = als[node*4 + g];
        int beg = coff[t*(NN+1) + node], end = coff[t*(NN+1) + node + 1];
        float ex = expf(lrelu(aself + ad));
        float dsum = ex;
        float2 hv = bf2x(*(const unsigned*)&h[(size_t)node*128 + lane*2]);
        float s0 = ex*hv.x, s1 = ex*hv.y;
        for (int e = beg; e < end; ++e) {
            int s = csrc[t*EE + e];
            float exx = expf(lrelu(als[s*4 + g] + ad));
            float2 hw = bf2x(*(const unsigned*)&h[(size_t)s*128 + lane*2]);
            dsum += exx; s0 += exx*hw.x; s1 += exx*hw.y;
        }
        float inv = 1.f/(dsum + 1e-16f);
        a0 += s0*inv; a1 += s1*inv;
    }
    int c0 = lane*2;
    a0 += bias3[c0]   + bias3[128+c0]   + bias3[256+c0];
    a1 += bias3[c0+1] + bias3[128+c0+1] + bias3[256+c0+1];
    float ssum = a0*a0 + a1*a1;
    #pragma unroll
    for (int o = 1; o < 64; o <<= 1) ssum += __shfl_xor(ssum, o);
    float r = rsqrtf(ssum*(1.f/128.f) + 1e-6f);
    size_t off = (size_t)node*128 + c0;
    float2 xo = *(const float2*)&xold[off];
    out[off]   = lrelu(xo.x + scale[c0]*a0*r);
    out[off+1] = lrelu(xo.y + scale[c0+1]*a1*r);
}

// ============ HGT aggregate (joint softmax over 3 types) + gelu, bf16 out ============
__global__ __launch_bounds__(256) void hgt_agg_k(const u16* __restrict__ ktb,
    const u16* __restrict__ vtb, const u16* __restrict__ qb,
    const float* __restrict__ prel, const int* __restrict__ coff,
    const int* __restrict__ csrc, u16* __restrict__ aggb)
{
    int gid = blockIdx.x*256 + threadIdx.x;
    int node = gid >> 6, lane = gid & 63;
    int hh = lane >> 4;
    float2 qv = bf2x(*(const unsigned*)&qb[(size_t)node*128 + lane*2]);
    float dsum = 0.f, a0 = 0.f, a1 = 0.f;
    for (int t = 0; t < 3; ++t) {
        float ph = prel[t*4 + hh] * 0.17677669529663689f;  // 1/sqrt(32)
        int beg = coff[t*(NN+1) + node], end = coff[t*(NN+1) + node + 1];
        const u16* kt = ktb + (size_t)t*ND;
        const u16* vt = vtb + (size_t)t*ND;
        for (int e = beg; e < end; ++e) {
            int s = csrc[t*EE + e];
            size_t ro = (size_t)s*128 + lane*2;
            float2 kv = bf2x(*(const unsigned*)&kt[ro]);
            float sc = qv.x*kv.x + qv.y*kv.y;
            #pragma unroll
            for (int o = 1; o < 16; o <<= 1) sc += __shfl_xor(sc, o);
            float ex = expf(sc * ph);
            float2 vx = bf2x(*(const unsigned*)&vt[ro]);
            dsum += ex; a0 += ex*vx.x; a1 += ex*vx.y;
        }
    }
    float inv = 1.f/(dsum + 1e-16f);
    size_t o = (size_t)node*128 + lane*2;
    aggb[o]   = f2bf(gelu_exact(a0*inv));
    aggb[o+1] = f2bf(gelu_exact(a1*inv));
}

// ============ FiLM small MLP: one block per batch row ============
__global__ __launch_bounds__(256) void film_k(const float* __restrict__ z,
    const float* __restrict__ W1, const float* __restrict__ b1,
    const float* __restrict__ W2, const float* __restrict__ b2,
    float* __restrict__ gb)
{
    __shared__ float zr[128];
    __shared__ float g1[256];
    int r = blockIdx.x, tid = threadIdx.x;
    if (tid < 128) zr[tid] = z[r*128 + tid];
    __syncthreads();
    float s = b1[tid];
    for (int k = 0; k < 128; ++k) s += zr[k]*W1[k*256 + tid];
    g1[tid] = gelu_exact(s);
    __syncthreads();
    float s2 = b2[tid];
    for (int k = 0; k < 256; ++k) s2 += g1[k]*W2[k*256 + tid];
    gb[r*256 + tid] = 0.1f*tanhf(s2);
}

// ================= launch =================
extern "C" void kernel_launch(void* const* d_in, const int* in_sizes, int n_in,
                              void* d_out, int out_size, void* d_ws, size_t ws_size,
                              hipStream_t stream)
{
    const float* x_cell = (const float*)d_in[0];
    const float* z_h    = (const float*)d_in[1];
    const float* x_emb  = (const float*)d_in[2];
    const int*   eidx   = (const int*)d_in[3];
    const int*   bszp   = (const int*)d_in[4];
    const float* g1W  = (const float*)d_in[5];
    const float* g1as = (const float*)d_in[6];
    const float* g1ad = (const float*)d_in[7];
    const float* g1b  = (const float*)d_in[8];
    const float* g2W  = (const float*)d_in[9];
    const float* g2as = (const float*)d_in[10];
    const float* g2ad = (const float*)d_in[11];
    const float* g2b  = (const float*)d_in[12];
    const float* n1s  = (const float*)d_in[13];
    const float* n2s  = (const float*)d_in[14];
    const float* n3s  = (const float*)d_in[15];
    const float* Wk   = (const float*)d_in[16];
    const float* bk   = (const float*)d_in[17];
    const float* Wq   = (const float*)d_in[18];
    const float* bq   = (const float*)d_in[19];
    const float* Wv   = (const float*)d_in[20];
    const float* bv   = (const float*)d_in[21];
    const float* arel = (const float*)d_in[22];
    const float* mrel = (const float*)d_in[23];
    const float* prel = (const float*)d_in[24];
    const float* Wo   = (const float*)d_in[25];
    const float* bo   = (const float*)d_in[26];
    const float* skipp= (const float*)d_in[27];
    const float* injW = (const float*)d_in[28];
    const float* injb = (const float*)d_in[29];
    const float* fW1  = (const float*)d_in[30];
    const float* fb1  = (const float*)d_in[31];
    const float* fW2  = (const float*)d_in[32];
    const float* fb2  = (const float*)d_in[33];

    // ---- workspace layout ----
    u16* wp   = (u16*)d_ws;                  // 17 * 16384 u16
    u16* wpa  = wp + (size_t)17*16384;       // 6 * 2048 u16
    float* x2   = (float*)(wpa + 6*2048);    // ND f32
    float* alsb = x2 + ND;                   // 3*NN*4
    float* aldb = alsb + (size_t)3*NN*4;     // 3*NN*4
    float* gbuf = aldb + (size_t)3*NN*4;     // 32*256
    int* coff   = (int*)(gbuf + 32*256);     // 3*(NN+1)
    int* csrc   = coff + 3*(NN+1);           // 3*EE
    int* tmpc   = csrc + 3*EE;               // 3*NN
    int* parts  = tmpc + 3*NN;               // 256
    u16* R1     = (u16*)(parts + 256);       // 3*ND u16
    u16* R2     = R1 + 3*ND;                 // 6*ND u16

    u16* hb  = R1;
    u16* qb  = R1 + ND;
    u16* ktb = R2;
    u16* vtb = R2 + 3*ND;
    u16* aggb = R1;                          // reuse slot 0 (dead after GAT)
    float* x1   = (float*)d_out;
    float* outp = (float*)d_out;

    const u16* wpg1 = wp;
    const u16* wpg2 = wp + (size_t)3*16384;
    const u16* wpk  = wp + (size_t)6*16384;
    const u16* wpq  = wp + (size_t)7*16384;
    const u16* wpv  = wp + (size_t)8*16384;
    const u16* wpo  = wp + (size_t)9*16384;
    const u16* wpinj= wp + (size_t)10*16384;
    const u16* wparel = wp + (size_t)11*16384;
    const u16* wpmrel = wp + (size_t)14*16384;

    // ---- weight pre-pack ----
    wpack_k<<<18, 256, 0, stream>>>(g1W, g2W, Wk, Wq, Wv, Wo, injW, arel, mrel,
                                    g1as, g1ad, g2as, g2ad, wp, wpa);

    // ---- CSR build (shared by GAT1, GAT2, HGT) ----
    hipMemsetAsync(tmpc, 0, 3*NN*sizeof(int), stream);
    hist_k<<<3*EE/256, 256, 0, stream>>>(eidx, tmpc);
    scan1_k<<<192, 256, 0, stream>>>(tmpc, coff, parts);
    scan2_k<<<1, 64, 0, stream>>>(parts);
    scan3_k<<<192, 256, 0, stream>>>(coff, parts);
    hipMemsetAsync(tmpc, 0, 3*NN*sizeof(int), stream);
    scatter_k<<<3*EE/256, 256, 0, stream>>>(eidx, coff, tmpc, csrc);

    // ---- FiLM small MLP ----
    int B = in_sizes[1] / 128;
    film_k<<<B, 256, 0, stream>>>(z_h, fW1, fb1, fW2, fb2, gbuf);

    // ---- GAT layer 1 ----
    gat_gemm3_k<<<512, 256, 0, stream>>>(x_cell, wpg1, wpa, hb, alsb, aldb);
    gat_aggres_k<<<16384, 256, 0, stream>>>(hb, alsb, aldb, coff, csrc, g1b, x_cell, n1s, x1);

    // ---- GAT layer 2 ----
    gat_gemm3_k<<<512, 256, 0, stream>>>(x1, wpg2, wpa + 3*2048, hb, alsb, aldb);
    gat_aggres_k<<<16384, 256, 0, stream>>>(hb, alsb, aldb, coff, csrc, g2b, x1, n2s, x2);

    // ---- HGT ----
    hgt_proj_k<<<512, 256, 0, stream>>>(x2, wpk, wpq, wpv, wparel, wpmrel,
                                        bk, bq, bv, qb, ktb, vtb);
    hgt_agg_k<<<16384, 256, 0, stream>>>(ktb, vtb, qb, prel, coff, csrc, aggb);

    // ---- final: Wo + residual + inject + FiLM ----
    final_k<<<1024, 256, 0, stream>>>(aggb, wpo, bo, x2, skipp, n3s,
                                      x_emb, wpinj, injb, gbuf, bszp, outp);
}